// Round 4
// baseline (4921.647 us; speedup 1.0000x reference)
//
#include <hip/hip_runtime.h>
#include <cstdint>
#include <cmath>

#define B_ 256
#define T_ 16
#define V_ 32000
#define E_ 256
#define H_ 512

typedef __attribute__((ext_vector_type(8))) short bf16x8;
typedef __attribute__((ext_vector_type(4))) float f32x4;

// ---------------- Threefry-2x32 (JAX-compatible) ----------------
__device__ __forceinline__ uint32_t rotl32(uint32_t x, int r) {
  return (x << r) | (x >> (32 - r));
}

__device__ __forceinline__ void tf2x32(uint32_t k0, uint32_t k1, uint32_t x0, uint32_t x1,
                                       uint32_t& o0, uint32_t& o1) {
  uint32_t k2 = k0 ^ k1 ^ 0x1BD11BDAu;
  x0 += k0; x1 += k1;
#define TFR(r) { x0 += x1; x1 = rotl32(x1, (r)); x1 ^= x0; }
  TFR(13) TFR(15) TFR(26) TFR(6)   x0 += k1; x1 += k2 + 1u;
  TFR(17) TFR(29) TFR(16) TFR(24)  x0 += k2; x1 += k0 + 2u;
  TFR(13) TFR(15) TFR(26) TFR(6)   x0 += k0; x1 += k1 + 3u;
  TFR(17) TFR(29) TFR(16) TFR(24)  x0 += k1; x1 += k2 + 4u;
  TFR(13) TFR(15) TFR(26) TFR(6)   x0 += k2; x1 += k0 + 5u;
#undef TFR
  o0 = x0; o1 = x1;
}

__device__ __forceinline__ float gumbel_from_bits(uint32_t bits) {
  uint32_t man = bits >> 9;
  float u;
  if (man == 0u) u = 1.17549435e-38f;
  else u = __uint_as_float(man | 0x3f800000u) - 1.0f;
  float inner = (float)log((double)u);            // < 0
  float outer = (float)log((double)(-inner));
  return -outer;
}

// round f32 -> bf16 bits (RTNE), value assumed finite
__device__ __forceinline__ uint32_t f2bf(float x) {
  uint32_t u = __float_as_uint(x);
  return (u + 0x7fffu + ((u >> 16) & 1u)) >> 16;
}

// ---------------- prep: interleaved (j,gate) weights, bias sums, step keys ----------------
__global__ __launch_bounds__(256) void prep_kernel(
    const float* __restrict__ wih0, const float* __restrict__ whh0,
    const float* __restrict__ wih1, const float* __restrict__ whh1,
    const float* __restrict__ bih0, const float* __restrict__ bhh0,
    const float* __restrict__ bih1, const float* __restrict__ bhh1,
    float* __restrict__ wq0, float* __restrict__ wq1,
    float* __restrict__ bq0, float* __restrict__ bq1, uint32_t* __restrict__ keys)
{
  const long long stride = (long long)gridDim.x * blockDim.x;
  const long long i0 = (long long)blockIdx.x * blockDim.x + threadIdx.x;
  if (i0 < 16) {
    uint32_t o0, o1;
    tf2x32(0u, 1u, 0u, (uint32_t)i0, o0, o1);   // split(key(1), 16)
    keys[2 * i0] = o0; keys[2 * i0 + 1] = o1;
  }
  const long long N0 = 2048LL * 768, N1 = 2048LL * 1024;
  const long long TOT = N0 + N1 + 2048 + 2048;
  for (long long i = i0; i < TOT; i += stride) {
    if (i < N0) {
      int n = (int)(i / 768), k = (int)(i % 768);
      int j = n >> 2, g = n & 3;
      int r = g * 512 + j;
      wq0[i] = (k < 256) ? wih0[r * 256 + k] : whh0[r * 512 + (k - 256)];
    } else if (i < N0 + N1) {
      long long q = i - N0;
      int n = (int)(q / 1024), k = (int)(q % 1024);
      int j = n >> 2, g = n & 3;
      int r = g * 512 + j;
      wq1[q] = (k < 512) ? wih1[r * 512 + k] : whh1[r * 512 + (k - 512)];
    } else if (i < N0 + N1 + 2048) {
      int n = (int)(i - N0 - N1);
      int j = n >> 2, g = n & 3;
      bq0[n] = bih0[g * 512 + j] + bhh0[g * 512 + j];
    } else {
      int n = (int)(i - N0 - N1 - 2048);
      int j = n >> 2, g = n & 3;
      bq1[n] = bih1[g * 512 + j] + bhh1[g * 512 + j];
    }
  }
}

// ---------------- prep B2: out_w f32 [32000][512] -> bf16-split [32000][1536] = [hi|lo|hi] --
__global__ __launch_bounds__(256) void prepB2_kernel(const float* __restrict__ w,
                                                     ushort* __restrict__ B2)
{
  const long long stride = (long long)gridDim.x * blockDim.x;
  for (long long i = (long long)blockIdx.x * blockDim.x + threadIdx.x;
       i < (long long)V_ * 512; i += stride) {
    int n = (int)(i >> 9), k = (int)(i & 511);
    float x = w[i];
    uint32_t hi = f2bf(x);
    float hf = __uint_as_float(hi << 16);
    uint32_t lo = f2bf(x - hf);
    ushort* row = B2 + (size_t)n * 1536;
    row[k] = (ushort)hi;
    row[512 + k] = (ushort)lo;
    row[1024 + k] = (ushort)hi;
  }
}

// ---------------- backbone: Linear + LayerNorm + exact GELU, state init ----------------
__global__ __launch_bounds__(256) void backbone_kernel(
    const float* __restrict__ x, const float* __restrict__ bb_w, const float* __restrict__ bb_b,
    const float* __restrict__ ln_g, const float* __restrict__ ln_b, const float* __restrict__ sos,
    float* __restrict__ xh0, float* __restrict__ xh1,
    float* __restrict__ c0, float* __restrict__ c1, int* __restrict__ done)
{
  const int b = blockIdx.x, tid = threadIdx.x;
  __shared__ float xs[E_];
  __shared__ float zs[H_];
  __shared__ float red[256];
  xs[tid] = x[b * E_ + tid];
  __syncthreads();
  for (int jj = 0; jj < 2; ++jj) {
    int j = jj * 256 + tid;
    float acc = 0.0f;
#pragma unroll 4
    for (int k = 0; k < E_; ++k) acc = fmaf(xs[k], bb_w[(size_t)j * E_ + k], acc);
    zs[j] = acc + bb_b[j];
  }
  __syncthreads();
  red[tid] = zs[tid] + zs[tid + 256];
  __syncthreads();
  for (int off = 128; off > 0; off >>= 1) { if (tid < off) red[tid] += red[tid + off]; __syncthreads(); }
  const float mu = red[0] / 512.0f;
  __syncthreads();
  {
    float d0 = zs[tid] - mu, d1 = zs[tid + 256] - mu;
    red[tid] = d0 * d0 + d1 * d1;
  }
  __syncthreads();
  for (int off = 128; off > 0; off >>= 1) { if (tid < off) red[tid] += red[tid + off]; __syncthreads(); }
  const float var = red[0] / 512.0f;
  const float sv = sqrtf(var + 1e-5f);
  for (int jj = 0; jj < 2; ++jj) {
    int j = jj * 256 + tid;
    float zn = (zs[j] - mu) / sv * ln_g[j] + ln_b[j];
    float h = 0.5f * zn * (1.0f + erff(zn / 1.41421356237309515f));
    xh0[(size_t)b * 768 + 256 + j] = h;        // h0 for step 0 cell0
    xh1[(size_t)b * 1024 + 512 + j] = 0.0f;    // h1 init
    c0[(size_t)b * 512 + j] = 0.0f;
    c1[(size_t)b * 512 + j] = 0.0f;
  }
  xh0[(size_t)b * 768 + tid] = sos[tid];       // inp init = sos
  if (tid == 0) done[b] = 0;
}

// ---------------- fused cell GEMM + LSTM update (TN must be 4: one hidden/thread) ----------
// optional dB second h-destination; optional A2 bf16-split ([hi|hi|lo]) destination
template<int MT, int NT, int TM, int TN>
__global__ __launch_bounds__(256) void gemm_lstm(
    const float* __restrict__ A, int lda,
    const float* __restrict__ W, int ldw,
    const float* __restrict__ bias,
    float* __restrict__ c,
    float* __restrict__ dA, int ldA,
    float* __restrict__ dB, int ldB,
    ushort* __restrict__ A2, int K)
{
  constexpr int KT = 16;
  __shared__ float As[KT][MT + 4];
  __shared__ float Ws[KT][NT + 4];
  const int tid = threadIdx.x;
  constexpr int NX = NT / TN;
  const int tx = tid % NX;
  const int ty = tid / NX;
  const int m0 = blockIdx.y * MT;
  const int n0 = blockIdx.x * NT;

  float acc[TM][TN];
#pragma unroll
  for (int i = 0; i < TM; ++i)
#pragma unroll
    for (int j = 0; j < TN; ++j) acc[i][j] = 0.0f;

  for (int kt = 0; kt < K; kt += KT) {
    __syncthreads();
    for (int e = tid; e < MT * KT / 4; e += 256) {
      int row = e / (KT / 4), kq = (e % (KT / 4)) * 4;
      float4 v = *(const float4*)&A[(size_t)(m0 + row) * lda + kt + kq];
      As[kq + 0][row] = v.x; As[kq + 1][row] = v.y;
      As[kq + 2][row] = v.z; As[kq + 3][row] = v.w;
    }
    for (int e = tid; e < NT * KT / 4; e += 256) {
      int row = e / (KT / 4), kq = (e % (KT / 4)) * 4;
      float4 v = *(const float4*)&W[(size_t)(n0 + row) * ldw + kt + kq];
      Ws[kq + 0][row] = v.x; Ws[kq + 1][row] = v.y;
      Ws[kq + 2][row] = v.z; Ws[kq + 3][row] = v.w;
    }
    __syncthreads();
#pragma unroll
    for (int k = 0; k < KT; ++k) {
      float a[TM], w[TN];
#pragma unroll
      for (int i = 0; i < TM; ++i) a[i] = As[k][ty * TM + i];
#pragma unroll
      for (int j = 0; j < TN; j += 4) *(float4*)&w[j] = *(const float4*)&Ws[k][tx * TN + j];
#pragma unroll
      for (int i = 0; i < TM; ++i)
#pragma unroll
        for (int j = 0; j < TN; ++j) acc[i][j] = fmaf(a[i], w[j], acc[i][j]);
    }
  }
  // LSTM epilogue: thread's 4 columns = gates i,f,g,o of hidden unit j
  const int n = n0 + tx * 4;
  const int j = n >> 2;
  const float b0 = bias[n], b1 = bias[n + 1], b2 = bias[n + 2], b3 = bias[n + 3];
#pragma unroll
  for (int i = 0; i < TM; ++i) {
    const int m = m0 + ty * TM + i;
    const float gi = acc[i][0] + b0;
    const float gf = acc[i][1] + b1;
    const float gg = acc[i][2] + b2;
    const float go = acc[i][3] + b3;
    const float si = 1.0f / (1.0f + expf(-gi));
    const float sf = 1.0f / (1.0f + expf(-gf));
    const float so = 1.0f / (1.0f + expf(-go));
    const float cn = sf * c[(size_t)m * 512 + j] + si * tanhf(gg);
    const float hn = so * tanhf(cn);
    c[(size_t)m * 512 + j] = cn;
    dA[(size_t)m * ldA + j] = hn;
    if (dB) dB[(size_t)m * ldB + j] = hn;
    if (A2) {
      uint32_t hi = f2bf(hn);
      float hf = __uint_as_float(hi << 16);
      uint32_t lo = f2bf(hn - hf);
      ushort* r = A2 + (size_t)m * 1536 + j;
      r[0]    = (ushort)hi;
      r[512]  = (ushort)hi;
      r[1024] = (ushort)lo;
    }
  }
}

// ---------------- fused bf16 MFMA logits GEMM + gumbel/softmax partials ----------------
// grid (2 m-blocks, 250 n-panels); 128x128 tile, BK=64, 4 waves (2x2), 4x4 frags 16x16x32.
// XOR-swizzled LDS staged via global_load_lds with pre-swizzled per-lane source.
// Epilogue: per row x 64-col wave chunk -> 8-float partial; logits never hit memory.
typedef const __attribute__((address_space(1))) void* as1_t;
typedef __attribute__((address_space(3))) void* as3_t;
__device__ __forceinline__ void glds16(const void* g, void* l) {
  __builtin_amdgcn_global_load_lds((as1_t)g, (as3_t)l, 16, 0, 0);
}

__global__ __launch_bounds__(256) void mfma_sample(
    const ushort* __restrict__ A2,   // [256][1536] bf16
    const ushort* __restrict__ B2,   // [32000][1536] bf16
    const float* __restrict__ bias,  // [32000]
    const uint32_t* __restrict__ keys, int t,
    float* __restrict__ partials)    // [256][500][8]
{
  __shared__ ushort lds[16384];      // 32 KB: A tile [128][64] @0, B tile @16KB
  const int tid = threadIdx.x;
  const int lane = tid & 63;
  const int wid = tid >> 6;
  const int wm = wid >> 1, wn = wid & 1;
  const int m0 = blockIdx.x * 128;   // 2 m-blocks (dispatch-adjacent share B2 panel)
  const int n0 = blockIdx.y * 128;   // 250 n-panels

  f32x4 acc[4][4];
#pragma unroll
  for (int i = 0; i < 4; ++i)
#pragma unroll
    for (int j = 0; j < 4; ++j)
#pragma unroll
      for (int q = 0; q < 4; ++q) acc[i][j][q] = 0.0f;

  for (int kc = 0; kc < 24; ++kc) {
    __syncthreads();
    const int kus = kc * 64;                       // k offset in ushort units
#pragma unroll
    for (int s = 0; s < 4; ++s) {
      const int o = (wid * 4 + s) * 1024 + lane * 16;   // byte offset in tile
      const int row = o >> 7;
      const int kb = (o >> 4) & 7;
      const int ksrc = kus + ((kb ^ (row & 7)) << 3);   // ushort offset within row
      glds16(A2 + (size_t)(m0 + row) * 1536 + ksrc,
             (void*)((char*)lds + (wid * 4 + s) * 1024));
      glds16(B2 + (size_t)(n0 + row) * 1536 + ksrc,
             (void*)((char*)lds + 16384 + (wid * 4 + s) * 1024));
    }
    asm volatile("s_waitcnt vmcnt(0)" ::: "memory");
    __syncthreads();
#pragma unroll
    for (int ks = 0; ks < 2; ++ks) {
      bf16x8 a[4], b[4];
      const int kb = ks * 4 + (lane >> 4);
#pragma unroll
      for (int i = 0; i < 4; ++i) {
        const int row = wm * 64 + i * 16 + (lane & 15);
        a[i] = *(const bf16x8*)((const char*)lds + row * 128 + ((kb ^ (row & 7)) << 4));
        const int col = wn * 64 + i * 16 + (lane & 15);
        b[i] = *(const bf16x8*)((const char*)lds + 16384 + col * 128 + ((kb ^ (col & 7)) << 4));
      }
#pragma unroll
      for (int i = 0; i < 4; ++i)
#pragma unroll
        for (int j = 0; j < 4; ++j)
          acc[i][j] = __builtin_amdgcn_mfma_f32_16x16x32_bf16(a[i], b[j], acc[i][j], 0, 0, 0);
    }
  }

  // ---- fused sampling epilogue ----
  const uint32_t k0 = keys[2 * t], k1 = keys[2 * t + 1];
  float bj[4];
#pragma unroll
  for (int j = 0; j < 4; ++j) bj[j] = bias[n0 + wn * 64 + j * 16 + (lane & 15)];
  const int colbase = n0 + wn * 64 + (lane & 15);
  const int pidx = blockIdx.y * 2 + wn;            // col-chunk index 0..499
#pragma unroll
  for (int i = 0; i < 4; ++i) {
#pragma unroll
    for (int q = 0; q < 4; ++q) {
      const int m = m0 + wm * 64 + i * 16 + (lane >> 4) * 4 + q;
      float l[4];
      float lmax = -INFINITY, sb = -INFINITY, lb = 0.0f; int ib = 0;
#pragma unroll
      for (int j = 0; j < 4; ++j) {
        l[j] = acc[i][j][q] + bj[j];
        const int v = colbase + j * 16;
        uint32_t o0, o1;
        tf2x32(k0, k1, 0u, (uint32_t)(m * V_ + v), o0, o1);
        const float s = l[j] + gumbel_from_bits(o0 ^ o1);
        lmax = fmaxf(lmax, l[j]);
        if (s > sb) { sb = s; ib = v; lb = l[j]; }
      }
      for (int o = 1; o < 16; o <<= 1) {
        float s2 = __shfl_xor(sb, o, 16);
        int   i2 = __shfl_xor(ib, o, 16);
        float l2 = __shfl_xor(lb, o, 16);
        if (s2 > sb || (s2 == sb && i2 < ib)) { sb = s2; ib = i2; lb = l2; }
        lmax = fmaxf(lmax, __shfl_xor(lmax, o, 16));
      }
      float S = 0.0f, Aa = 0.0f;
#pragma unroll
      for (int j = 0; j < 4; ++j) {
        const float d = l[j] - lmax;
        const float e = expf(d);
        S += e; Aa = fmaf(e, d, Aa);
      }
      for (int o = 1; o < 16; o <<= 1) {
        S  += __shfl_xor(S, o, 16);
        Aa += __shfl_xor(Aa, o, 16);
      }
      if ((lane & 15) == 0) {
        float* dst = partials + ((size_t)m * 500 + pidx) * 8;
        *(float4*)dst       = make_float4(lmax, S, Aa, sb);
        *(float4*)(dst + 4) = make_float4(__int_as_float(ib), lb, 0.0f, 0.0f);
      }
    }
  }
}

// ---------------- merge 500 partials: token, logp, entropy, feedback ----------------
__global__ __launch_bounds__(256) void merge_sample(
    const float* __restrict__ partials, const float* __restrict__ emb,
    int t, int* __restrict__ done, float* __restrict__ xh0next,
    float* __restrict__ ids, float* __restrict__ logp, float* __restrict__ ent)
{
  const int b = blockIdx.x, tid = threadIdx.x;
  float M0 = -INFINITY, S0 = 0.0f, A0 = 0.0f;
  float M1 = -INFINITY, S1 = 0.0f, A1 = 0.0f;
  float sb = -INFINITY, lb = 0.0f;
  int ib = 0x7fffffff;
  {
    const float* src = partials + ((size_t)b * 500 + tid) * 8;
    float4 p0 = *(const float4*)src;
    float4 p1 = *(const float4*)(src + 4);
    M0 = p0.x; S0 = p0.y; A0 = p0.z; sb = p0.w;
    ib = __float_as_int(p1.x); lb = p1.y;
  }
  if (tid + 256 < 500) {
    const float* src = partials + ((size_t)b * 500 + tid + 256) * 8;
    float4 p0 = *(const float4*)src;
    float4 p1 = *(const float4*)(src + 4);
    M1 = p0.x; S1 = p0.y; A1 = p0.z;
    float s2 = p0.w; int i2 = __float_as_int(p1.x);
    if (s2 > sb || (s2 == sb && i2 < ib)) { sb = s2; ib = i2; lb = p1.y; }
  }
  __shared__ float sm[256], ss[256], sa[256], sv[256], sl[256];
  __shared__ int si[256];
  sm[tid] = fmaxf(M0, M1); __syncthreads();
  for (int o = 128; o > 0; o >>= 1) { if (tid < o) sm[tid] = fmaxf(sm[tid], sm[tid + o]); __syncthreads(); }
  const float Mg = sm[0];
  const float w0 = (S0 > 0.0f) ? expf(M0 - Mg) : 0.0f;
  const float w1 = (S1 > 0.0f) ? expf(M1 - Mg) : 0.0f;
  ss[tid] = S0 * w0 + S1 * w1;
  sa[tid] = ((S0 > 0.0f) ? w0 * (A0 + (M0 - Mg) * S0) : 0.0f)
          + ((S1 > 0.0f) ? w1 * (A1 + (M1 - Mg) * S1) : 0.0f);
  sv[tid] = sb; si[tid] = ib; sl[tid] = lb;
  __syncthreads();
  for (int o = 128; o > 0; o >>= 1) {
    if (tid < o) {
      ss[tid] += ss[tid + o]; sa[tid] += sa[tid + o];
      float v2 = sv[tid + o]; int i2 = si[tid + o];
      if (v2 > sv[tid] || (v2 == sv[tid] && i2 < si[tid])) {
        sv[tid] = v2; si[tid] = i2; sl[tid] = sl[tid + o];
      }
    }
    __syncthreads();
  }
  if (tid == 0) {
    const float Sg = ss[0], Ag = sa[0];
    const float logS = logf(Sg);
    const int tok = si[0];
    const float lp = sl[0] - Mg - logS;
    const float en = logS - Ag / Sg;
    const int dn = done[b];
    const int tokm = dn ? 0 : tok;
    ids[b * T_ + t]  = (float)tokm;
    logp[b * T_ + t] = dn ? 0.0f : lp;
    ent[b * T_ + t]  = dn ? 0.0f : en;
    done[b] = dn | (tokm == 0);
    si[0] = tokm;
  }
  __syncthreads();
  const int tk = si[0];
  xh0next[(size_t)b * 768 + tid] = emb[(size_t)tk * E_ + tid];
}

// ---------------- lengths + trailing-zero, then one-hot msg fill ----------------
__global__ void len_kernel(float* __restrict__ ids, float* __restrict__ lens) {
  const int b = threadIdx.x;  // 256 threads, 1 block
  int len = T_; bool has = false;
  for (int t = 0; t < T_; ++t) {
    if (!has && ids[b * T_ + t] == 0.0f) { has = true; len = t + 1; }
  }
  for (int t = len - 1; t < T_; ++t) ids[b * T_ + t] = 0.0f;
  lens[b] = (float)len;
}

__global__ __launch_bounds__(256) void msg_kernel(const float* __restrict__ ids,
                                                  float* __restrict__ msg) {
  const int bt = blockIdx.x;            // 4096 = B*T
  const int id = (int)ids[bt];
  float4* dst = (float4*)(msg + (size_t)bt * V_);
  for (int q = threadIdx.x; q < V_ / 4; q += 256) {
    const int v = q * 4;
    float4 val;
    val.x = (v     == id) ? 1.0f : 0.0f;
    val.y = (v + 1 == id) ? 1.0f : 0.0f;
    val.z = (v + 2 == id) ? 1.0f : 0.0f;
    val.w = (v + 3 == id) ? 1.0f : 0.0f;
    dst[q] = val;
  }
}

// ---------------- launcher ----------------
extern "C" void kernel_launch(void* const* d_in, const int* in_sizes, int n_in,
                              void* d_out, int out_size, void* d_ws, size_t ws_size,
                              hipStream_t stream) {
  const float* x    = (const float*)d_in[0];
  const float* bb_w = (const float*)d_in[1];
  const float* bb_b = (const float*)d_in[2];
  const float* ln_g = (const float*)d_in[3];
  const float* ln_b = (const float*)d_in[4];
  const float* emb  = (const float*)d_in[5];
  const float* sos  = (const float*)d_in[6];
  const float* wih0 = (const float*)d_in[7];
  const float* whh0 = (const float*)d_in[8];
  const float* bih0 = (const float*)d_in[9];
  const float* bhh0 = (const float*)d_in[10];
  const float* wih1 = (const float*)d_in[11];
  const float* whh1 = (const float*)d_in[12];
  const float* bih1 = (const float*)d_in[13];
  const float* bhh1 = (const float*)d_in[14];
  const float* out_w = (const float*)d_in[15];
  const float* out_b = (const float*)d_in[16];

  float* out  = (float*)d_out;
  float* ids  = out;                                  // [B,T]   4096
  float* msg  = out + 4096;                           // [B,T,V] 131072000
  float* logp = out + 131076096;                      // [B,T]   4096
  float* ent  = out + 131080192;                      // [B,T]   4096
  float* lens = out + 131084288;                      // [B]     256

  // scratch inside msg region (rewritten at the end)
  float* p = msg;
  float* wq0  = p; p += 1572864;
  float* wq1  = p; p += 2097152;
  float* bq0  = p; p += 2048;
  float* bq1  = p; p += 2048;
  float* xh0a = p; p += 196608;
  float* xh0b = p; p += 196608;
  float* xh1a = p; p += 262144;
  float* xh1b = p; p += 262144;
  float* c0   = p; p += 131072;
  float* c1   = p; p += 131072;
  float* partials = p; p += 1024000;                  // 256*500*8
  uint32_t* keys = (uint32_t*)p; p += 64;
  int* done = (int*)p; p += 256;
  ushort* A2 = (ushort*)p; p += 196608;               // 256*1536 bf16
  ushort* B2 = (ushort*)p; p += 24576000;             // 32000*1536 bf16

  prep_kernel<<<2048, 256, 0, stream>>>(wih0, whh0, wih1, whh1,
                                        bih0, bhh0, bih1, bhh1,
                                        wq0, wq1, bq0, bq1, keys);
  prepB2_kernel<<<4096, 256, 0, stream>>>(out_w, B2);
  backbone_kernel<<<256, 256, 0, stream>>>(x, bb_w, bb_b, ln_g, ln_b, sos,
                                           xh0a, xh1a, c0, c1, done);
  for (int t = 0; t < T_; ++t) {
    float* x0c = (t & 1) ? xh0b : xh0a;
    float* x0n = (t & 1) ? xh0a : xh0b;
    float* x1c = (t & 1) ? xh1b : xh1a;
    float* x1n = (t & 1) ? xh1a : xh1b;
    // cell 0: reads [inp|h0] -> h0_new into xh1 cur (first half) + xh0 next (+256)
    gemm_lstm<32, 64, 2, 4><<<dim3(32, 8), 256, 0, stream>>>(
        x0c, 768, wq0, 768, bq0, c0, x1c, 1024, x0n + 256, 768, nullptr, 768);
    // cell 1: reads [h0_new|h1] -> h1_new into xh1 next (+512) + A2 bf16-split
    gemm_lstm<32, 64, 2, 4><<<dim3(32, 8), 256, 0, stream>>>(
        x1c, 1024, wq1, 1024, bq1, c1, x1n + 512, 1024, nullptr, 0, A2, 1024);
    // fused logits + sampling partials (logits never materialized)
    mfma_sample<<<dim3(2, 250), 256, 0, stream>>>(A2, B2, out_b, keys, t, partials);
    merge_sample<<<256, 256, 0, stream>>>(partials, emb, t, done, x0n,
                                          ids, logp, ent);
  }
  len_kernel<<<1, 256, 0, stream>>>(ids, lens);
  msg_kernel<<<4096, 256, 0, stream>>>(ids, msg);
}

// Round 5
// 3472.552 us; speedup vs baseline: 1.4173x; 1.4173x over previous
//
#include <hip/hip_runtime.h>
#include <cstdint>
#include <cmath>

#define B_ 256
#define T_ 16
#define V_ 32000
#define E_ 256
#define H_ 512

typedef __attribute__((ext_vector_type(8))) short bf16x8;
typedef __attribute__((ext_vector_type(4))) float f32x4;

// ---------------- Threefry-2x32 (JAX-compatible) ----------------
__device__ __forceinline__ uint32_t rotl32(uint32_t x, int r) {
  return (x << r) | (x >> (32 - r));
}

__device__ __forceinline__ void tf2x32(uint32_t k0, uint32_t k1, uint32_t x0, uint32_t x1,
                                       uint32_t& o0, uint32_t& o1) {
  uint32_t k2 = k0 ^ k1 ^ 0x1BD11BDAu;
  x0 += k0; x1 += k1;
#define TFR(r) { x0 += x1; x1 = rotl32(x1, (r)); x1 ^= x0; }
  TFR(13) TFR(15) TFR(26) TFR(6)   x0 += k1; x1 += k2 + 1u;
  TFR(17) TFR(29) TFR(16) TFR(24)  x0 += k2; x1 += k0 + 2u;
  TFR(13) TFR(15) TFR(26) TFR(6)   x0 += k0; x1 += k1 + 3u;
  TFR(17) TFR(29) TFR(16) TFR(24)  x0 += k1; x1 += k2 + 4u;
  TFR(13) TFR(15) TFR(26) TFR(6)   x0 += k2; x1 += k0 + 5u;
#undef TFR
  o0 = x0; o1 = x1;
}

__device__ __forceinline__ float gumbel_from_bits(uint32_t bits) {
  uint32_t man = bits >> 9;
  float u;
  if (man == 0u) u = 1.17549435e-38f;
  else u = __uint_as_float(man | 0x3f800000u) - 1.0f;
  float inner = (float)log((double)u);            // < 0
  float outer = (float)log((double)(-inner));
  return -outer;
}

// round f32 -> bf16 bits (RTNE), value assumed finite
__device__ __forceinline__ uint32_t f2bf(float x) {
  uint32_t u = __float_as_uint(x);
  return (u + 0x7fffu + ((u >> 16) & 1u)) >> 16;
}

// ---------------- prep: interleaved (j,gate) weights, bias sums, step keys ----------------
__global__ __launch_bounds__(256) void prep_kernel(
    const float* __restrict__ wih0, const float* __restrict__ whh0,
    const float* __restrict__ wih1, const float* __restrict__ whh1,
    const float* __restrict__ bih0, const float* __restrict__ bhh0,
    const float* __restrict__ bih1, const float* __restrict__ bhh1,
    float* __restrict__ wq0, float* __restrict__ wq1,
    float* __restrict__ bq0, float* __restrict__ bq1, uint32_t* __restrict__ keys)
{
  const long long stride = (long long)gridDim.x * blockDim.x;
  const long long i0 = (long long)blockIdx.x * blockDim.x + threadIdx.x;
  if (i0 < 16) {
    uint32_t o0, o1;
    tf2x32(0u, 1u, 0u, (uint32_t)i0, o0, o1);   // split(key(1), 16)
    keys[2 * i0] = o0; keys[2 * i0 + 1] = o1;
  }
  const long long N0 = 2048LL * 768, N1 = 2048LL * 1024;
  const long long TOT = N0 + N1 + 2048 + 2048;
  for (long long i = i0; i < TOT; i += stride) {
    if (i < N0) {
      int n = (int)(i / 768), k = (int)(i % 768);
      int j = n >> 2, g = n & 3;
      int r = g * 512 + j;
      wq0[i] = (k < 256) ? wih0[r * 256 + k] : whh0[r * 512 + (k - 256)];
    } else if (i < N0 + N1) {
      long long q = i - N0;
      int n = (int)(q / 1024), k = (int)(q % 1024);
      int j = n >> 2, g = n & 3;
      int r = g * 512 + j;
      wq1[q] = (k < 512) ? wih1[r * 512 + k] : whh1[r * 512 + (k - 512)];
    } else if (i < N0 + N1 + 2048) {
      int n = (int)(i - N0 - N1);
      int j = n >> 2, g = n & 3;
      bq0[n] = bih0[g * 512 + j] + bhh0[g * 512 + j];
    } else {
      int n = (int)(i - N0 - N1 - 2048);
      int j = n >> 2, g = n & 3;
      bq1[n] = bih1[g * 512 + j] + bhh1[g * 512 + j];
    }
  }
}

// ---------------- prep B2: out_w f32 [32000][512] -> bf16-split [32000][1536] = [hi|lo|hi] --
__global__ __launch_bounds__(256) void prepB2_kernel(const float* __restrict__ w,
                                                     ushort* __restrict__ B2)
{
  const long long stride = (long long)gridDim.x * blockDim.x;
  for (long long i = (long long)blockIdx.x * blockDim.x + threadIdx.x;
       i < (long long)V_ * 512; i += stride) {
    int n = (int)(i >> 9), k = (int)(i & 511);
    float x = w[i];
    uint32_t hi = f2bf(x);
    float hf = __uint_as_float(hi << 16);
    uint32_t lo = f2bf(x - hf);
    ushort* row = B2 + (size_t)n * 1536;
    row[k] = (ushort)hi;
    row[512 + k] = (ushort)lo;
    row[1024 + k] = (ushort)hi;
  }
}

// ---------------- backbone: Linear + LayerNorm + exact GELU, state init ----------------
__global__ __launch_bounds__(256) void backbone_kernel(
    const float* __restrict__ x, const float* __restrict__ bb_w, const float* __restrict__ bb_b,
    const float* __restrict__ ln_g, const float* __restrict__ ln_b, const float* __restrict__ sos,
    float* __restrict__ xh0, float* __restrict__ xh1,
    float* __restrict__ c0, float* __restrict__ c1, int* __restrict__ done)
{
  const int b = blockIdx.x, tid = threadIdx.x;
  __shared__ float xs[E_];
  __shared__ float zs[H_];
  __shared__ float red[256];
  xs[tid] = x[b * E_ + tid];
  __syncthreads();
  for (int jj = 0; jj < 2; ++jj) {
    int j = jj * 256 + tid;
    float acc = 0.0f;
#pragma unroll 4
    for (int k = 0; k < E_; ++k) acc = fmaf(xs[k], bb_w[(size_t)j * E_ + k], acc);
    zs[j] = acc + bb_b[j];
  }
  __syncthreads();
  red[tid] = zs[tid] + zs[tid + 256];
  __syncthreads();
  for (int off = 128; off > 0; off >>= 1) { if (tid < off) red[tid] += red[tid + off]; __syncthreads(); }
  const float mu = red[0] / 512.0f;
  __syncthreads();
  {
    float d0 = zs[tid] - mu, d1 = zs[tid + 256] - mu;
    red[tid] = d0 * d0 + d1 * d1;
  }
  __syncthreads();
  for (int off = 128; off > 0; off >>= 1) { if (tid < off) red[tid] += red[tid + off]; __syncthreads(); }
  const float var = red[0] / 512.0f;
  const float sv = sqrtf(var + 1e-5f);
  for (int jj = 0; jj < 2; ++jj) {
    int j = jj * 256 + tid;
    float zn = (zs[j] - mu) / sv * ln_g[j] + ln_b[j];
    float h = 0.5f * zn * (1.0f + erff(zn / 1.41421356237309515f));
    xh0[(size_t)b * 768 + 256 + j] = h;        // h0 for step 0 cell0
    xh1[(size_t)b * 1024 + 512 + j] = 0.0f;    // h1 init
    c0[(size_t)b * 512 + j] = 0.0f;
    c1[(size_t)b * 512 + j] = 0.0f;
  }
  xh0[(size_t)b * 768 + tid] = sos[tid];       // inp init = sos
  if (tid == 0) done[b] = 0;
}

// ---------------- fused cell GEMM + LSTM update (TN must be 4: one hidden/thread) ----------
// optional dB second h-destination; optional A2 bf16-split ([hi|hi|lo]) destination
template<int MT, int NT, int TM, int TN>
__global__ __launch_bounds__(256) void gemm_lstm(
    const float* __restrict__ A, int lda,
    const float* __restrict__ W, int ldw,
    const float* __restrict__ bias,
    float* __restrict__ c,
    float* __restrict__ dA, int ldA,
    float* __restrict__ dB, int ldB,
    ushort* __restrict__ A2, int K)
{
  constexpr int KT = 16;
  __shared__ float As[KT][MT + 4];
  __shared__ float Ws[KT][NT + 4];
  const int tid = threadIdx.x;
  constexpr int NX = NT / TN;
  const int tx = tid % NX;
  const int ty = tid / NX;
  const int m0 = blockIdx.y * MT;
  const int n0 = blockIdx.x * NT;

  float acc[TM][TN];
#pragma unroll
  for (int i = 0; i < TM; ++i)
#pragma unroll
    for (int j = 0; j < TN; ++j) acc[i][j] = 0.0f;

  for (int kt = 0; kt < K; kt += KT) {
    __syncthreads();
    for (int e = tid; e < MT * KT / 4; e += 256) {
      int row = e / (KT / 4), kq = (e % (KT / 4)) * 4;
      float4 v = *(const float4*)&A[(size_t)(m0 + row) * lda + kt + kq];
      As[kq + 0][row] = v.x; As[kq + 1][row] = v.y;
      As[kq + 2][row] = v.z; As[kq + 3][row] = v.w;
    }
    for (int e = tid; e < NT * KT / 4; e += 256) {
      int row = e / (KT / 4), kq = (e % (KT / 4)) * 4;
      float4 v = *(const float4*)&W[(size_t)(n0 + row) * ldw + kt + kq];
      Ws[kq + 0][row] = v.x; Ws[kq + 1][row] = v.y;
      Ws[kq + 2][row] = v.z; Ws[kq + 3][row] = v.w;
    }
    __syncthreads();
#pragma unroll
    for (int k = 0; k < KT; ++k) {
      float a[TM], w[TN];
#pragma unroll
      for (int i = 0; i < TM; ++i) a[i] = As[k][ty * TM + i];
#pragma unroll
      for (int j = 0; j < TN; j += 4) *(float4*)&w[j] = *(const float4*)&Ws[k][tx * TN + j];
#pragma unroll
      for (int i = 0; i < TM; ++i)
#pragma unroll
        for (int j = 0; j < TN; ++j) acc[i][j] = fmaf(a[i], w[j], acc[i][j]);
    }
  }
  // LSTM epilogue: thread's 4 columns = gates i,f,g,o of hidden unit j
  const int n = n0 + tx * 4;
  const int j = n >> 2;
  const float b0 = bias[n], b1 = bias[n + 1], b2 = bias[n + 2], b3 = bias[n + 3];
#pragma unroll
  for (int i = 0; i < TM; ++i) {
    const int m = m0 + ty * TM + i;
    const float gi = acc[i][0] + b0;
    const float gf = acc[i][1] + b1;
    const float gg = acc[i][2] + b2;
    const float go = acc[i][3] + b3;
    const float si = 1.0f / (1.0f + expf(-gi));
    const float sf = 1.0f / (1.0f + expf(-gf));
    const float so = 1.0f / (1.0f + expf(-go));
    const float cn = sf * c[(size_t)m * 512 + j] + si * tanhf(gg);
    const float hn = so * tanhf(cn);
    c[(size_t)m * 512 + j] = cn;
    dA[(size_t)m * ldA + j] = hn;
    if (dB) dB[(size_t)m * ldB + j] = hn;
    if (A2) {
      uint32_t hi = f2bf(hn);
      float hf = __uint_as_float(hi << 16);
      uint32_t lo = f2bf(hn - hf);
      ushort* r = A2 + (size_t)m * 1536 + j;
      r[0]    = (ushort)hi;
      r[512]  = (ushort)hi;
      r[1024] = (ushort)lo;
    }
  }
}

// ---------------- bf16 MFMA logits GEMM: [256][1536] x [32000][1536]^T + bias -> f32 -------
// 128x128 tile, BK=64, 4 waves (2x2), 4x4 frags of 16x16x32. XOR-swizzled LDS staged via
// global_load_lds with pre-swizzled per-lane source (linear LDS dest). Proven in round 3.
typedef const __attribute__((address_space(1))) void* as1_t;
typedef __attribute__((address_space(3))) void* as3_t;
__device__ __forceinline__ void glds16(const void* g, void* l) {
  __builtin_amdgcn_global_load_lds((as1_t)g, (as3_t)l, 16, 0, 0);
}

__global__ __launch_bounds__(256) void mfma_logits(
    const ushort* __restrict__ A2,   // [256][1536] bf16
    const ushort* __restrict__ B2,   // [32000][1536] bf16
    const float* __restrict__ bias,  // [32000]
    float* __restrict__ logits)      // [256][32000] f32
{
  __shared__ ushort lds[16384];      // 32 KB: A tile [128][64] @0, B tile @16KB
  const int tid = threadIdx.x;
  const int lane = tid & 63;
  const int wid = tid >> 6;
  const int wm = wid >> 1, wn = wid & 1;
  const int m0 = blockIdx.y * 128;
  const int n0 = blockIdx.x * 128;

  f32x4 acc[4][4];
#pragma unroll
  for (int i = 0; i < 4; ++i)
#pragma unroll
    for (int j = 0; j < 4; ++j)
#pragma unroll
      for (int q = 0; q < 4; ++q) acc[i][j][q] = 0.0f;

  for (int kc = 0; kc < 24; ++kc) {
    __syncthreads();
    const int kus = kc * 64;                       // k offset in ushort units
#pragma unroll
    for (int s = 0; s < 4; ++s) {
      const int o = (wid * 4 + s) * 1024 + lane * 16;   // byte offset in tile
      const int row = o >> 7;
      const int kb = (o >> 4) & 7;
      const int ksrc = kus + ((kb ^ (row & 7)) << 3);   // ushort offset within row
      glds16(A2 + (size_t)(m0 + row) * 1536 + ksrc,
             (void*)((char*)lds + (wid * 4 + s) * 1024));
      glds16(B2 + (size_t)(n0 + row) * 1536 + ksrc,
             (void*)((char*)lds + 16384 + (wid * 4 + s) * 1024));
    }
    asm volatile("s_waitcnt vmcnt(0)" ::: "memory");
    __syncthreads();
#pragma unroll
    for (int ks = 0; ks < 2; ++ks) {
      bf16x8 a[4], b[4];
      const int kb = ks * 4 + (lane >> 4);
#pragma unroll
      for (int i = 0; i < 4; ++i) {
        const int row = wm * 64 + i * 16 + (lane & 15);
        a[i] = *(const bf16x8*)((const char*)lds + row * 128 + ((kb ^ (row & 7)) << 4));
        const int col = wn * 64 + i * 16 + (lane & 15);
        b[i] = *(const bf16x8*)((const char*)lds + 16384 + col * 128 + ((kb ^ (col & 7)) << 4));
      }
#pragma unroll
      for (int i = 0; i < 4; ++i)
#pragma unroll
        for (int j = 0; j < 4; ++j)
          acc[i][j] = __builtin_amdgcn_mfma_f32_16x16x32_bf16(a[i], b[j], acc[i][j], 0, 0, 0);
    }
  }
  float bj[4];
#pragma unroll
  for (int j = 0; j < 4; ++j) bj[j] = bias[n0 + wn * 64 + j * 16 + (lane & 15)];
  const int rbase = (lane >> 4) * 4;
#pragma unroll
  for (int i = 0; i < 4; ++i) {
    const int m = m0 + wm * 64 + i * 16 + rbase;
#pragma unroll
    for (int j = 0; j < 4; ++j) {
      const int n = n0 + wn * 64 + j * 16 + (lane & 15);
#pragma unroll
      for (int q = 0; q < 4; ++q)
        logits[(size_t)(m + q) * V_ + n] = acc[i][j][q] + bj[j];
    }
  }
}

// ---------------- sample_row: one block per batch row, full fused sampling ----------------
// 512 threads; pass1 max/argmax(l+gumbel), pass2 exp-sums (row L2-resident);
// writes ids/logp/ent, done, emb feedback; at t==15 also lengths + tail-zero.
__global__ __launch_bounds__(512) void sample_row(
    const float* __restrict__ logits, const uint32_t* __restrict__ keys, int t,
    const float* __restrict__ emb, int* __restrict__ done,
    float* __restrict__ xh0next, float* __restrict__ ids,
    float* __restrict__ logp, float* __restrict__ ent, float* __restrict__ lens)
{
  const int b = blockIdx.x, tid = threadIdx.x;
  const uint32_t k0 = keys[2 * t], k1 = keys[2 * t + 1];
  const float* lrow = logits + (size_t)b * V_;

  float lmax = -INFINITY, sb = -INFINITY, lb = 0.0f; int ib = 0;
  for (int idx = tid; idx < V_ / 4; idx += 512) {
    float4 l4 = *(const float4*)&lrow[idx * 4];
    const float le[4] = {l4.x, l4.y, l4.z, l4.w};
#pragma unroll
    for (int e = 0; e < 4; ++e) {
      const int v = idx * 4 + e;
      uint32_t o0, o1;
      tf2x32(k0, k1, 0u, (uint32_t)(b * V_ + v), o0, o1);
      const float s = le[e] + gumbel_from_bits(o0 ^ o1);
      lmax = fmaxf(lmax, le[e]);
      if (s > sb) { sb = s; ib = v; lb = le[e]; }
    }
  }
  __shared__ float sm[512], sv[512], sl[512];
  __shared__ int si[512];
  sm[tid] = lmax; sv[tid] = sb; si[tid] = ib; sl[tid] = lb;
  __syncthreads();
  for (int o = 256; o > 0; o >>= 1) {
    if (tid < o) {
      sm[tid] = fmaxf(sm[tid], sm[tid + o]);
      float v2 = sv[tid + o]; int i2 = si[tid + o];
      if (v2 > sv[tid] || (v2 == sv[tid] && i2 < si[tid])) {
        sv[tid] = v2; si[tid] = i2; sl[tid] = sl[tid + o];
      }
    }
    __syncthreads();
  }
  const float m = sm[0];
  const int tok = si[0];
  const float l_tok = sl[0];
  __syncthreads();

  float S = 0.0f, Aa = 0.0f;
  for (int idx = tid; idx < V_ / 4; idx += 512) {
    float4 l4 = *(const float4*)&lrow[idx * 4];
    const float le[4] = {l4.x, l4.y, l4.z, l4.w};
#pragma unroll
    for (int e = 0; e < 4; ++e) {
      const float d = le[e] - m;
      const float ex = expf(d);
      S += ex; Aa = fmaf(ex, d, Aa);
    }
  }
  __shared__ float ss[512], sa[512];
  ss[tid] = S; sa[tid] = Aa;
  __syncthreads();
  for (int o = 256; o > 0; o >>= 1) {
    if (tid < o) { ss[tid] += ss[tid + o]; sa[tid] += sa[tid + o]; }
    __syncthreads();
  }
  if (tid == 0) {
    const float Ssum = ss[0], Asum = sa[0];
    const float logS = logf(Ssum);
    const float lp = l_tok - m - logS;
    const float en = logS - Asum / Ssum;
    const int dn = done[b];
    const int tokm = dn ? 0 : tok;
    ids[b * T_ + t]  = (float)tokm;
    logp[b * T_ + t] = dn ? 0.0f : lp;
    ent[b * T_ + t]  = dn ? 0.0f : en;
    done[b] = dn | (tokm == 0);
    si[0] = tokm;
    if (t == T_ - 1) {
      int len = T_; bool has = false;
      for (int tt = 0; tt < T_; ++tt) {
        if (!has && ids[b * T_ + tt] == 0.0f) { has = true; len = tt + 1; }
      }
      for (int tt = len - 1; tt < T_; ++tt) ids[b * T_ + tt] = 0.0f;
      lens[b] = (float)len;
    }
  }
  __syncthreads();
  const int tk = si[0];
  if (tid < E_) xh0next[(size_t)b * 768 + tid] = emb[(size_t)tk * E_ + tid];
}

// ---------------- one-hot msg fill ----------------
__global__ __launch_bounds__(256) void msg_kernel(const float* __restrict__ ids,
                                                  float* __restrict__ msg) {
  const int bt = blockIdx.x;            // 4096 = B*T
  const int id = (int)ids[bt];
  float4* dst = (float4*)(msg + (size_t)bt * V_);
  for (int q = threadIdx.x; q < V_ / 4; q += 256) {
    const int v = q * 4;
    float4 val;
    val.x = (v     == id) ? 1.0f : 0.0f;
    val.y = (v + 1 == id) ? 1.0f : 0.0f;
    val.z = (v + 2 == id) ? 1.0f : 0.0f;
    val.w = (v + 3 == id) ? 1.0f : 0.0f;
    dst[q] = val;
  }
}

// ---------------- launcher ----------------
extern "C" void kernel_launch(void* const* d_in, const int* in_sizes, int n_in,
                              void* d_out, int out_size, void* d_ws, size_t ws_size,
                              hipStream_t stream) {
  const float* x    = (const float*)d_in[0];
  const float* bb_w = (const float*)d_in[1];
  const float* bb_b = (const float*)d_in[2];
  const float* ln_g = (const float*)d_in[3];
  const float* ln_b = (const float*)d_in[4];
  const float* emb  = (const float*)d_in[5];
  const float* sos  = (const float*)d_in[6];
  const float* wih0 = (const float*)d_in[7];
  const float* whh0 = (const float*)d_in[8];
  const float* bih0 = (const float*)d_in[9];
  const float* bhh0 = (const float*)d_in[10];
  const float* wih1 = (const float*)d_in[11];
  const float* whh1 = (const float*)d_in[12];
  const float* bih1 = (const float*)d_in[13];
  const float* bhh1 = (const float*)d_in[14];
  const float* out_w = (const float*)d_in[15];
  const float* out_b = (const float*)d_in[16];

  float* out  = (float*)d_out;
  float* ids  = out;                                  // [B,T]   4096
  float* msg  = out + 4096;                           // [B,T,V] 131072000
  float* logp = out + 131076096;                      // [B,T]   4096
  float* ent  = out + 131080192;                      // [B,T]   4096
  float* lens = out + 131084288;                      // [B]     256

  // scratch inside msg region (rewritten at the end)
  float* p = msg;
  float* wq0  = p; p += 1572864;
  float* wq1  = p; p += 2097152;
  float* bq0  = p; p += 2048;
  float* bq1  = p; p += 2048;
  float* xh0a = p; p += 196608;
  float* xh0b = p; p += 196608;
  float* xh1a = p; p += 262144;
  float* xh1b = p; p += 262144;
  float* c0   = p; p += 131072;
  float* c1   = p; p += 131072;
  uint32_t* keys = (uint32_t*)p; p += 64;
  int* done = (int*)p; p += 256;
  ushort* A2 = (ushort*)p; p += 196608;               // 256*1536 bf16
  ushort* B2 = (ushort*)p; p += 24576000;             // 32000*1536 bf16
  float* logits = p; p += 8192000;                    // 256*32000 f32

  prep_kernel<<<2048, 256, 0, stream>>>(wih0, whh0, wih1, whh1,
                                        bih0, bhh0, bih1, bhh1,
                                        wq0, wq1, bq0, bq1, keys);
  prepB2_kernel<<<4096, 256, 0, stream>>>(out_w, B2);
  backbone_kernel<<<256, 256, 0, stream>>>(x, bb_w, bb_b, ln_g, ln_b, sos,
                                           xh0a, xh1a, c0, c1, done);
  for (int t = 0; t < T_; ++t) {
    float* x0c = (t & 1) ? xh0b : xh0a;
    float* x0n = (t & 1) ? xh0a : xh0b;
    float* x1c = (t & 1) ? xh1b : xh1a;
    float* x1n = (t & 1) ? xh1a : xh1b;
    // cell 0: reads [inp|h0] -> h0_new into xh1 cur (first half) + xh0 next (+256)
    gemm_lstm<32, 64, 2, 4><<<dim3(32, 8), 256, 0, stream>>>(
        x0c, 768, wq0, 768, bq0, c0, x1c, 1024, x0n + 256, 768, nullptr, 768);
    // cell 1: reads [h0_new|h1] -> h1_new into xh1 next (+512) + A2 bf16-split
    gemm_lstm<32, 64, 2, 4><<<dim3(32, 8), 256, 0, stream>>>(
        x1c, 1024, wq1, 1024, bq1, c1, x1n + 512, 1024, nullptr, 0, A2, 1024);
    // logits (f32, materialized)
    mfma_logits<<<dim3(250, 2), 256, 0, stream>>>(A2, B2, out_b, logits);
    // fused sampling: argmax + softmax stats + feedback (+lengths at t=15)
    sample_row<<<256, 512, 0, stream>>>(logits, keys, t, emb, done,
                                        x0n, ids, logp, ent, lens);
  }
  msg_kernel<<<4096, 256, 0, stream>>>(ids, msg);
}

// Round 6
// 2823.065 us; speedup vs baseline: 1.7434x; 1.2301x over previous
//
#include <hip/hip_runtime.h>
#include <cstdint>
#include <cmath>

#define B_ 256
#define T_ 16
#define V_ 32000
#define E_ 256
#define H_ 512

typedef __attribute__((ext_vector_type(8))) short bf16x8;
typedef __attribute__((ext_vector_type(4))) float f32x4;

// ---------------- Threefry-2x32 (JAX-compatible) ----------------
__device__ __forceinline__ uint32_t rotl32(uint32_t x, int r) {
  return (x << r) | (x >> (32 - r));
}

__device__ __forceinline__ void tf2x32(uint32_t k0, uint32_t k1, uint32_t x0, uint32_t x1,
                                       uint32_t& o0, uint32_t& o1) {
  uint32_t k2 = k0 ^ k1 ^ 0x1BD11BDAu;
  x0 += k0; x1 += k1;
#define TFR(r) { x0 += x1; x1 = rotl32(x1, (r)); x1 ^= x0; }
  TFR(13) TFR(15) TFR(26) TFR(6)   x0 += k1; x1 += k2 + 1u;
  TFR(17) TFR(29) TFR(16) TFR(24)  x0 += k2; x1 += k0 + 2u;
  TFR(13) TFR(15) TFR(26) TFR(6)   x0 += k0; x1 += k1 + 3u;
  TFR(17) TFR(29) TFR(16) TFR(24)  x0 += k1; x1 += k2 + 4u;
  TFR(13) TFR(15) TFR(26) TFR(6)   x0 += k2; x1 += k0 + 5u;
#undef TFR
  o0 = x0; o1 = x1;
}

__device__ __forceinline__ float gumbel_from_bits(uint32_t bits) {
  uint32_t man = bits >> 9;
  float u;
  if (man == 0u) u = 1.17549435e-38f;
  else u = __uint_as_float(man | 0x3f800000u) - 1.0f;
  float inner = (float)log((double)u);            // < 0
  float outer = (float)log((double)(-inner));
  return -outer;
}

// round f32 -> bf16 bits (RTNE), value assumed finite
__device__ __forceinline__ uint32_t f2bf(float x) {
  uint32_t u = __float_as_uint(x);
  return (u + 0x7fffu + ((u >> 16) & 1u)) >> 16;
}

typedef const __attribute__((address_space(1))) void* as1_t;
typedef __attribute__((address_space(3))) void* as3_t;
__device__ __forceinline__ void glds16(const void* g, void* l) {
  __builtin_amdgcn_global_load_lds((as1_t)g, (as3_t)l, 16, 0, 0);
}

// ---------------- prep cell weights: bf16 3-term [hi|lo|hi], interleaved (j,gate) ----------
// W3 [2048][3K]; bq[n] = bih+bhh. Also writes step keys when keys != nullptr.
__global__ __launch_bounds__(256) void prepW3_kernel(
    const float* __restrict__ wih, const float* __restrict__ whh,
    const float* __restrict__ bih, const float* __restrict__ bhh,
    ushort* __restrict__ W3, float* __restrict__ bq, int E, uint32_t* __restrict__ keys)
{
  const int K = E + 512;
  const long long tot = 2048LL * K;
  const long long stride = (long long)gridDim.x * blockDim.x;
  const long long i0 = (long long)blockIdx.x * blockDim.x + threadIdx.x;
  if (keys && i0 < 16) {
    uint32_t o0, o1;
    tf2x32(0u, 1u, 0u, (uint32_t)i0, o0, o1);   // split(key(1), 16)
    keys[2 * i0] = o0; keys[2 * i0 + 1] = o1;
  }
  for (long long i = i0; i < tot + 2048; i += stride) {
    if (i < tot) {
      int n = (int)(i / K), k = (int)(i % K);
      int j = n >> 2, g = n & 3;
      int r = g * 512 + j;
      float x = (k < E) ? wih[(size_t)r * E + k] : whh[(size_t)r * 512 + (k - E)];
      uint32_t hi = f2bf(x);
      float hf = __uint_as_float(hi << 16);
      uint32_t lo = f2bf(x - hf);
      ushort* row = W3 + (size_t)n * 3 * K;
      row[k] = (ushort)hi;
      row[K + k] = (ushort)lo;
      row[2 * K + k] = (ushort)hi;
    } else {
      int n = (int)(i - tot);
      int j = n >> 2, g = n & 3;
      bq[n] = bih[g * 512 + j] + bhh[g * 512 + j];
    }
  }
}

// ---------------- prep B2: out_w f32 [32000][512] -> bf16-split [32000][1536] = [hi|lo|hi] --
__global__ __launch_bounds__(256) void prepB2_kernel(const float* __restrict__ w,
                                                     ushort* __restrict__ B2)
{
  const long long stride = (long long)gridDim.x * blockDim.x;
  for (long long i = (long long)blockIdx.x * blockDim.x + threadIdx.x;
       i < (long long)V_ * 512; i += stride) {
    int n = (int)(i >> 9), k = (int)(i & 511);
    float x = w[i];
    uint32_t hi = f2bf(x);
    float hf = __uint_as_float(hi << 16);
    uint32_t lo = f2bf(x - hf);
    ushort* row = B2 + (size_t)n * 1536;
    row[k] = (ushort)hi;
    row[512 + k] = (ushort)lo;
    row[1024 + k] = (ushort)hi;
  }
}

// ---------------- backbone: Linear + LayerNorm + exact GELU, state init ----------------
// writes A0a (cell0 input triples: sos + h0) and A1a h1-slots = 0; c0,c1 = 0
__global__ __launch_bounds__(256) void backbone_kernel(
    const float* __restrict__ x, const float* __restrict__ bb_w, const float* __restrict__ bb_b,
    const float* __restrict__ ln_g, const float* __restrict__ ln_b, const float* __restrict__ sos,
    ushort* __restrict__ A0a, ushort* __restrict__ A1a,
    float* __restrict__ c0, float* __restrict__ c1, int* __restrict__ done)
{
  const int b = blockIdx.x, tid = threadIdx.x;
  __shared__ float xs[E_];
  __shared__ float zs[H_];
  __shared__ float red[256];
  xs[tid] = x[b * E_ + tid];
  __syncthreads();
  for (int jj = 0; jj < 2; ++jj) {
    int j = jj * 256 + tid;
    float acc = 0.0f;
#pragma unroll 4
    for (int k = 0; k < E_; ++k) acc = fmaf(xs[k], bb_w[(size_t)j * E_ + k], acc);
    zs[j] = acc + bb_b[j];
  }
  __syncthreads();
  red[tid] = zs[tid] + zs[tid + 256];
  __syncthreads();
  for (int off = 128; off > 0; off >>= 1) { if (tid < off) red[tid] += red[tid + off]; __syncthreads(); }
  const float mu = red[0] / 512.0f;
  __syncthreads();
  {
    float d0 = zs[tid] - mu, d1 = zs[tid + 256] - mu;
    red[tid] = d0 * d0 + d1 * d1;
  }
  __syncthreads();
  for (int off = 128; off > 0; off >>= 1) { if (tid < off) red[tid] += red[tid + off]; __syncthreads(); }
  const float var = red[0] / 512.0f;
  const float sv = sqrtf(var + 1e-5f);
  for (int jj = 0; jj < 2; ++jj) {
    int j = jj * 256 + tid;
    float zn = (zs[j] - mu) / sv * ln_g[j] + ln_b[j];
    float h = 0.5f * zn * (1.0f + erff(zn / 1.41421356237309515f));
    uint32_t hi = f2bf(h);
    float hf = __uint_as_float(hi << 16);
    uint32_t lo = f2bf(h - hf);
    A0a[(size_t)b * 2304 + 256 + j]  = (ushort)hi;   // h0 hi (chunk0)
    A0a[(size_t)b * 2304 + 1024 + j] = (ushort)hi;   // h0 hi (chunk1)
    A0a[(size_t)b * 2304 + 1792 + j] = (ushort)lo;   // h0 lo (chunk2)
    A1a[(size_t)b * 3072 + 512 + j]  = 0;            // h1 = 0
    A1a[(size_t)b * 3072 + 1536 + j] = 0;
    A1a[(size_t)b * 3072 + 2560 + j] = 0;
    c0[(size_t)b * 512 + j] = 0.0f;
    c1[(size_t)b * 512 + j] = 0.0f;
  }
  {
    const float xv = sos[tid];
    uint32_t hi = f2bf(xv);
    float hf = __uint_as_float(hi << 16);
    uint32_t lo = f2bf(xv - hf);
    A0a[(size_t)b * 2304 + tid]        = (ushort)hi;  // x hi (chunk0)
    A0a[(size_t)b * 2304 + 768 + tid]  = (ushort)hi;  // x hi (chunk1)
    A0a[(size_t)b * 2304 + 1536 + tid] = (ushort)lo;  // x lo (chunk2)
  }
  if (tid == 0) done[b] = 0;
}

// ---------------- split-bf16 MFMA LSTM cell: gates GEMM + LSTM update ----------------
// A3 [256][K3], W3 [2048][K3] bf16; 64x64 tile, 4 waves (2x2), BK=64, XOR-swizzled LDS.
// Epilogue: gates -> LDS transpose -> sigmoid/tanh -> c (f32) + h as bf16 triples to 2 dests.
template<int KC>
__global__ __launch_bounds__(256) void mfma_lstm(
    const ushort* __restrict__ A3, const ushort* __restrict__ W3,
    const float* __restrict__ bias, float* __restrict__ c,
    ushort* __restrict__ d1, int rs1, int o1a, int o1b, int o1c,
    ushort* __restrict__ d2, int rs2, int o2a, int o2b, int o2c)
{
  constexpr int K3 = KC * 64;
  __shared__ float smem[64 * 65];            // 16.6 KB; staging alias (16 KB) + gate transpose
  ushort* lds = (ushort*)smem;               // A tile [64][64] @0, W tile @8KB
  const int tid = threadIdx.x;
  const int lane = tid & 63;
  const int wid = tid >> 6;
  const int wm = wid >> 1, wn = wid & 1;
  const int m0 = blockIdx.y * 64;
  const int n0 = blockIdx.x * 64;

  f32x4 acc[2][2];
#pragma unroll
  for (int i = 0; i < 2; ++i)
#pragma unroll
    for (int j = 0; j < 2; ++j)
#pragma unroll
      for (int q = 0; q < 4; ++q) acc[i][j][q] = 0.0f;

  for (int kc = 0; kc < KC; ++kc) {
    __syncthreads();
    const int kus = kc * 64;
#pragma unroll
    for (int s = 0; s < 2; ++s) {
      const int o = (wid * 2 + s) * 1024 + lane * 16;   // byte offset in 8 KB tile
      const int row = o >> 7;
      const int kb = (o >> 4) & 7;
      const int ksrc = kus + ((kb ^ (row & 7)) << 3);
      glds16(A3 + (size_t)(m0 + row) * K3 + ksrc,
             (void*)((char*)lds + (wid * 2 + s) * 1024));
      glds16(W3 + (size_t)(n0 + row) * K3 + ksrc,
             (void*)((char*)lds + 8192 + (wid * 2 + s) * 1024));
    }
    asm volatile("s_waitcnt vmcnt(0)" ::: "memory");
    __syncthreads();
#pragma unroll
    for (int ks = 0; ks < 2; ++ks) {
      bf16x8 a[2], w[2];
      const int kb = ks * 4 + (lane >> 4);
#pragma unroll
      for (int i = 0; i < 2; ++i) {
        const int row = wm * 32 + i * 16 + (lane & 15);
        a[i] = *(const bf16x8*)((const char*)lds + row * 128 + ((kb ^ (row & 7)) << 4));
        const int col = wn * 32 + i * 16 + (lane & 15);
        w[i] = *(const bf16x8*)((const char*)lds + 8192 + col * 128 + ((kb ^ (col & 7)) << 4));
      }
#pragma unroll
      for (int i = 0; i < 2; ++i)
#pragma unroll
        for (int j = 0; j < 2; ++j)
          acc[i][j] = __builtin_amdgcn_mfma_f32_16x16x32_bf16(a[i], w[j], acc[i][j], 0, 0, 0);
    }
  }
  // dump gates to LDS (f32, padded stride 65)
  __syncthreads();
#pragma unroll
  for (int i = 0; i < 2; ++i)
#pragma unroll
    for (int j = 0; j < 2; ++j)
#pragma unroll
      for (int q = 0; q < 4; ++q)
        smem[(wm * 32 + i * 16 + (lane >> 4) * 4 + q) * 65 + wn * 32 + j * 16 + (lane & 15)]
            = acc[i][j][q];
  __syncthreads();
  // thread -> (row = tid>>2, units (tid&3)*4+e); gates are 4 consecutive cols per unit
  const int row = tid >> 2;
  const int m = m0 + row;
#pragma unroll
  for (int e = 0; e < 4; ++e) {
    const int ul = (tid & 3) * 4 + e;        // local unit 0..15
    const int nc = ul * 4;                   // local col base
    const float gi = smem[row * 65 + nc + 0] + bias[n0 + nc + 0];
    const float gf = smem[row * 65 + nc + 1] + bias[n0 + nc + 1];
    const float gg = smem[row * 65 + nc + 2] + bias[n0 + nc + 2];
    const float go = smem[row * 65 + nc + 3] + bias[n0 + nc + 3];
    const int u = (n0 >> 2) + ul;            // global hidden unit
    const float si = 1.0f / (1.0f + expf(-gi));
    const float sf = 1.0f / (1.0f + expf(-gf));
    const float so = 1.0f / (1.0f + expf(-go));
    const float cn = sf * c[(size_t)m * 512 + u] + si * tanhf(gg);
    const float hn = so * tanhf(cn);
    c[(size_t)m * 512 + u] = cn;
    const uint32_t hi = f2bf(hn);
    const float hf = __uint_as_float(hi << 16);
    const uint32_t lo = f2bf(hn - hf);
    d1[(size_t)m * rs1 + o1a + u] = (ushort)hi;
    d1[(size_t)m * rs1 + o1b + u] = (ushort)hi;
    d1[(size_t)m * rs1 + o1c + u] = (ushort)lo;
    d2[(size_t)m * rs2 + o2a + u] = (ushort)hi;
    d2[(size_t)m * rs2 + o2b + u] = (ushort)hi;
    d2[(size_t)m * rs2 + o2c + u] = (ushort)lo;
  }
}

// ---------------- bf16 MFMA logits GEMM: [256][1536] x [32000][1536]^T + bias -> f32 -------
// 128x128 tile, BK=64, 4 waves (2x2), 4x4 frags of 16x16x32. Proven in round 3.
__global__ __launch_bounds__(256) void mfma_logits(
    const ushort* __restrict__ A2,   // [256][1536] bf16
    const ushort* __restrict__ B2,   // [32000][1536] bf16
    const float* __restrict__ bias,  // [32000]
    float* __restrict__ logits)      // [256][32000] f32
{
  __shared__ ushort lds[16384];      // 32 KB: A tile [128][64] @0, B tile @16KB
  const int tid = threadIdx.x;
  const int lane = tid & 63;
  const int wid = tid >> 6;
  const int wm = wid >> 1, wn = wid & 1;
  const int m0 = blockIdx.y * 128;
  const int n0 = blockIdx.x * 128;

  f32x4 acc[4][4];
#pragma unroll
  for (int i = 0; i < 4; ++i)
#pragma unroll
    for (int j = 0; j < 4; ++j)
#pragma unroll
      for (int q = 0; q < 4; ++q) acc[i][j][q] = 0.0f;

  for (int kc = 0; kc < 24; ++kc) {
    __syncthreads();
    const int kus = kc * 64;                       // k offset in ushort units
#pragma unroll
    for (int s = 0; s < 4; ++s) {
      const int o = (wid * 4 + s) * 1024 + lane * 16;   // byte offset in tile
      const int row = o >> 7;
      const int kb = (o >> 4) & 7;
      const int ksrc = kus + ((kb ^ (row & 7)) << 3);   // ushort offset within row
      glds16(A2 + (size_t)(m0 + row) * 1536 + ksrc,
             (void*)((char*)lds + (wid * 4 + s) * 1024));
      glds16(B2 + (size_t)(n0 + row) * 1536 + ksrc,
             (void*)((char*)lds + 16384 + (wid * 4 + s) * 1024));
    }
    asm volatile("s_waitcnt vmcnt(0)" ::: "memory");
    __syncthreads();
#pragma unroll
    for (int ks = 0; ks < 2; ++ks) {
      bf16x8 a[4], b[4];
      const int kb = ks * 4 + (lane >> 4);
#pragma unroll
      for (int i = 0; i < 4; ++i) {
        const int row = wm * 64 + i * 16 + (lane & 15);
        a[i] = *(const bf16x8*)((const char*)lds + row * 128 + ((kb ^ (row & 7)) << 4));
        const int col = wn * 64 + i * 16 + (lane & 15);
        b[i] = *(const bf16x8*)((const char*)lds + 16384 + col * 128 + ((kb ^ (col & 7)) << 4));
      }
#pragma unroll
      for (int i = 0; i < 4; ++i)
#pragma unroll
        for (int j = 0; j < 4; ++j)
          acc[i][j] = __builtin_amdgcn_mfma_f32_16x16x32_bf16(a[i], b[j], acc[i][j], 0, 0, 0);
    }
  }
  float bj[4];
#pragma unroll
  for (int j = 0; j < 4; ++j) bj[j] = bias[n0 + wn * 64 + j * 16 + (lane & 15)];
  const int rbase = (lane >> 4) * 4;
#pragma unroll
  for (int i = 0; i < 4; ++i) {
    const int m = m0 + wm * 64 + i * 16 + rbase;
#pragma unroll
    for (int j = 0; j < 4; ++j) {
      const int n = n0 + wn * 64 + j * 16 + (lane & 15);
#pragma unroll
      for (int q = 0; q < 4; ++q)
        logits[(size_t)(m + q) * V_ + n] = acc[i][j][q] + bj[j];
    }
  }
}

// ---------------- sample_row: one pass (m=0), fused feedback as bf16 triple ----------------
__global__ __launch_bounds__(512) void sample_row(
    const float* __restrict__ logits, const uint32_t* __restrict__ keys, int t,
    const float* __restrict__ emb, int* __restrict__ done,
    ushort* __restrict__ A0next, float* __restrict__ ids,
    float* __restrict__ logp, float* __restrict__ ent, float* __restrict__ lens)
{
  const int b = blockIdx.x, tid = threadIdx.x;
  const uint32_t k0 = keys[2 * t], k1 = keys[2 * t + 1];
  const float* lrow = logits + (size_t)b * V_;

  float S = 0.0f, Aa = 0.0f, sb = -INFINITY, lb = 0.0f; int ib = 0;
  for (int idx = tid; idx < V_ / 4; idx += 512) {
    float4 l4 = *(const float4*)&lrow[idx * 4];
    const float le[4] = {l4.x, l4.y, l4.z, l4.w};
#pragma unroll
    for (int e = 0; e < 4; ++e) {
      const int v = idx * 4 + e;
      uint32_t o0, o1;
      tf2x32(k0, k1, 0u, (uint32_t)(b * V_ + v), o0, o1);
      const float s = le[e] + gumbel_from_bits(o0 ^ o1);
      if (s > sb) { sb = s; ib = v; lb = le[e]; }
      const float ex = expf(le[e]);          // |l| < ~1: no overflow, skip max-shift
      S += ex; Aa = fmaf(ex, le[e], Aa);
    }
  }
  __shared__ float ss[512], sa[512], sv[512], sl[512];
  __shared__ int si[512];
  ss[tid] = S; sa[tid] = Aa; sv[tid] = sb; si[tid] = ib; sl[tid] = lb;
  __syncthreads();
  for (int o = 256; o > 0; o >>= 1) {
    if (tid < o) {
      ss[tid] += ss[tid + o]; sa[tid] += sa[tid + o];
      float v2 = sv[tid + o]; int i2 = si[tid + o];
      if (v2 > sv[tid] || (v2 == sv[tid] && i2 < si[tid])) {
        sv[tid] = v2; si[tid] = i2; sl[tid] = sl[tid + o];
      }
    }
    __syncthreads();
  }
  if (tid == 0) {
    const float Ssum = ss[0], Asum = sa[0];
    const float logS = logf(Ssum);
    const int tok = si[0];
    const float lp = sl[0] - logS;
    const float en = logS - Asum / Ssum;
    const int dn = done[b];
    const int tokm = dn ? 0 : tok;
    ids[b * T_ + t]  = (float)tokm;
    logp[b * T_ + t] = dn ? 0.0f : lp;
    ent[b * T_ + t]  = dn ? 0.0f : en;
    done[b] = dn | (tokm == 0);
    si[0] = tokm;
    if (t == T_ - 1) {
      int len = T_; bool has = false;
      for (int tt = 0; tt < T_; ++tt) {
        if (!has && ids[b * T_ + tt] == 0.0f) { has = true; len = tt + 1; }
      }
      for (int tt = len - 1; tt < T_; ++tt) ids[b * T_ + tt] = 0.0f;
      lens[b] = (float)len;
    }
  }
  __syncthreads();
  const int tk = si[0];
  if (tid < E_) {
    const float xv = emb[(size_t)tk * E_ + tid];
    const uint32_t hi = f2bf(xv);
    const float hf = __uint_as_float(hi << 16);
    const uint32_t lo = f2bf(xv - hf);
    A0next[(size_t)b * 2304 + tid]        = (ushort)hi;
    A0next[(size_t)b * 2304 + 768 + tid]  = (ushort)hi;
    A0next[(size_t)b * 2304 + 1536 + tid] = (ushort)lo;
  }
}

// ---------------- one-hot msg fill ----------------
__global__ __launch_bounds__(256) void msg_kernel(const float* __restrict__ ids,
                                                  float* __restrict__ msg) {
  const int bt = blockIdx.x;            // 4096 = B*T
  const int id = (int)ids[bt];
  float4* dst = (float4*)(msg + (size_t)bt * V_);
  for (int q = threadIdx.x; q < V_ / 4; q += 256) {
    const int v = q * 4;
    float4 val;
    val.x = (v     == id) ? 1.0f : 0.0f;
    val.y = (v + 1 == id) ? 1.0f : 0.0f;
    val.z = (v + 2 == id) ? 1.0f : 0.0f;
    val.w = (v + 3 == id) ? 1.0f : 0.0f;
    dst[q] = val;
  }
}

// ---------------- launcher ----------------
extern "C" void kernel_launch(void* const* d_in, const int* in_sizes, int n_in,
                              void* d_out, int out_size, void* d_ws, size_t ws_size,
                              hipStream_t stream) {
  const float* x    = (const float*)d_in[0];
  const float* bb_w = (const float*)d_in[1];
  const float* bb_b = (const float*)d_in[2];
  const float* ln_g = (const float*)d_in[3];
  const float* ln_b = (const float*)d_in[4];
  const float* emb  = (const float*)d_in[5];
  const float* sos  = (const float*)d_in[6];
  const float* wih0 = (const float*)d_in[7];
  const float* whh0 = (const float*)d_in[8];
  const float* bih0 = (const float*)d_in[9];
  const float* bhh0 = (const float*)d_in[10];
  const float* wih1 = (const float*)d_in[11];
  const float* whh1 = (const float*)d_in[12];
  const float* bih1 = (const float*)d_in[13];
  const float* bhh1 = (const float*)d_in[14];
  const float* out_w = (const float*)d_in[15];
  const float* out_b = (const float*)d_in[16];

  float* out  = (float*)d_out;
  float* ids  = out;                                  // [B,T]   4096
  float* msg  = out + 4096;                           // [B,T,V] 131072000
  float* logp = out + 131076096;                      // [B,T]   4096
  float* ent  = out + 131080192;                      // [B,T]   4096
  float* lens = out + 131084288;                      // [B]     256

  // scratch inside msg region (rewritten at the end); all float-count offsets
  float* p = msg;
  ushort* W30 = (ushort*)p; p += 2359296;             // 2048*2304 bf16
  ushort* W31 = (ushort*)p; p += 3145728;             // 2048*3072 bf16
  float* bq0 = p; p += 2048;
  float* bq1 = p; p += 2048;
  ushort* A0a = (ushort*)p; p += 294912;              // 256*2304 bf16
  ushort* A0b = (ushort*)p; p += 294912;
  ushort* A1a = (ushort*)p; p += 393216;              // 256*3072 bf16
  ushort* A1b = (ushort*)p; p += 393216;
  float* c0 = p; p += 131072;
  float* c1 = p; p += 131072;
  ushort* A2 = (ushort*)p; p += 196608;               // 256*1536 bf16
  ushort* B2 = (ushort*)p; p += 24576000;             // 32000*1536 bf16
  float* logits = p; p += 8192000;                    // 256*32000 f32
  uint32_t* keys = (uint32_t*)p; p += 64;
  int* done = (int*)p; p += 256;

  prepW3_kernel<<<2048, 256, 0, stream>>>(wih0, whh0, bih0, bhh0, W30, bq0, 256, keys);
  prepW3_kernel<<<2048, 256, 0, stream>>>(wih1, whh1, bih1, bhh1, W31, bq1, 512, nullptr);
  prepB2_kernel<<<4096, 256, 0, stream>>>(out_w, B2);
  backbone_kernel<<<256, 256, 0, stream>>>(x, bb_w, bb_b, ln_g, ln_b, sos,
                                           A0a, A1a, c0, c1, done);
  for (int t = 0; t < T_; ++t) {
    ushort* A0c = (t & 1) ? A0b : A0a;
    ushort* A0n = (t & 1) ? A0a : A0b;
    ushort* A1c = (t & 1) ? A1b : A1a;
    ushort* A1n = (t & 1) ? A1a : A1b;
    // cell 0: h0 -> A1 cur (h0 slots) + A0 next (h slots)
    mfma_lstm<36><<<dim3(32, 4), 256, 0, stream>>>(
        A0c, W30, bq0, c0,
        A1c, 3072, 0, 1024, 2048,
        A0n, 2304, 256, 1024, 1792);
    // cell 1: h1 -> A1 next (h1 slots) + A2 (logits input)
    mfma_lstm<48><<<dim3(32, 4), 256, 0, stream>>>(
        A1c, W31, bq1, c1,
        A1n, 3072, 512, 1536, 2560,
        A2, 1536, 0, 512, 1024);
    // logits (f32, materialized)
    mfma_logits<<<dim3(250, 2), 256, 0, stream>>>(A2, B2, out_b, logits);
    // fused sampling: one pass, argmax + softmax stats + feedback (+lengths at t=15)
    sample_row<<<256, 512, 0, stream>>>(logits, keys, t, emb, done,
                                        A0n, ids, logp, ent, lens);
  }
  msg_kernel<<<4096, 256, 0, stream>>>(ids, msg);
}

// Round 7
// 2500.990 us; speedup vs baseline: 1.9679x; 1.1288x over previous
//
#include <hip/hip_runtime.h>
#include <cstdint>
#include <cmath>

#define B_ 256
#define T_ 16
#define V_ 32000
#define E_ 256
#define H_ 512

typedef __attribute__((ext_vector_type(8))) short bf16x8;
typedef __attribute__((ext_vector_type(4))) float f32x4;

// ---------------- Threefry-2x32 (JAX-compatible) ----------------
__device__ __forceinline__ uint32_t rotl32(uint32_t x, int r) {
  return (x << r) | (x >> (32 - r));
}

__device__ __forceinline__ void tf2x32(uint32_t k0, uint32_t k1, uint32_t x0, uint32_t x1,
                                       uint32_t& o0, uint32_t& o1) {
  uint32_t k2 = k0 ^ k1 ^ 0x1BD11BDAu;
  x0 += k0; x1 += k1;
#define TFR(r) { x0 += x1; x1 = rotl32(x1, (r)); x1 ^= x0; }
  TFR(13) TFR(15) TFR(26) TFR(6)   x0 += k1; x1 += k2 + 1u;
  TFR(17) TFR(29) TFR(16) TFR(24)  x0 += k2; x1 += k0 + 2u;
  TFR(13) TFR(15) TFR(26) TFR(6)   x0 += k0; x1 += k1 + 3u;
  TFR(17) TFR(29) TFR(16) TFR(24)  x0 += k1; x1 += k2 + 4u;
  TFR(13) TFR(15) TFR(26) TFR(6)   x0 += k2; x1 += k0 + 5u;
#undef TFR
  o0 = x0; o1 = x1;
}

__device__ __forceinline__ float gumbel_from_bits(uint32_t bits) {
  uint32_t man = bits >> 9;
  float u;
  if (man == 0u) u = 1.17549435e-38f;
  else u = __uint_as_float(man | 0x3f800000u) - 1.0f;
  float inner = (float)log((double)u);            // < 0
  float outer = (float)log((double)(-inner));
  return -outer;
}

// round f32 -> bf16 bits (RTNE), value assumed finite
__device__ __forceinline__ uint32_t f2bf(float x) {
  uint32_t u = __float_as_uint(x);
  return (u + 0x7fffu + ((u >> 16) & 1u)) >> 16;
}

typedef const __attribute__((address_space(1))) void* as1_t;
typedef __attribute__((address_space(3))) void* as3_t;
__device__ __forceinline__ void glds16(const void* g, void* l) {
  __builtin_amdgcn_global_load_lds((as1_t)g, (as3_t)l, 16, 0, 0);
}

// ---------------- prep cell weights: bf16 3-term [hi|lo|hi], interleaved (j,gate) ----------
__global__ __launch_bounds__(256) void prepW3_kernel(
    const float* __restrict__ wih, const float* __restrict__ whh,
    const float* __restrict__ bih, const float* __restrict__ bhh,
    ushort* __restrict__ W3, float* __restrict__ bq, int E, uint32_t* __restrict__ keys)
{
  const int K = E + 512;
  const long long tot = 2048LL * K;
  const long long stride = (long long)gridDim.x * blockDim.x;
  const long long i0 = (long long)blockIdx.x * blockDim.x + threadIdx.x;
  if (keys && i0 < 16) {
    uint32_t o0, o1;
    tf2x32(0u, 1u, 0u, (uint32_t)i0, o0, o1);   // split(key(1), 16)
    keys[2 * i0] = o0; keys[2 * i0 + 1] = o1;
  }
  for (long long i = i0; i < tot + 2048; i += stride) {
    if (i < tot) {
      int n = (int)(i / K), k = (int)(i % K);
      int j = n >> 2, g = n & 3;
      int r = g * 512 + j;
      float x = (k < E) ? wih[(size_t)r * E + k] : whh[(size_t)r * 512 + (k - E)];
      uint32_t hi = f2bf(x);
      float hf = __uint_as_float(hi << 16);
      uint32_t lo = f2bf(x - hf);
      ushort* row = W3 + (size_t)n * 3 * K;
      row[k] = (ushort)hi;
      row[K + k] = (ushort)lo;
      row[2 * K + k] = (ushort)hi;
    } else {
      int n = (int)(i - tot);
      int j = n >> 2, g = n & 3;
      bq[n] = bih[g * 512 + j] + bhh[g * 512 + j];
    }
  }
}

// ---------------- prep B2: out_w f32 [32000][512] -> bf16-split [32000][1536] = [hi|lo|hi] --
__global__ __launch_bounds__(256) void prepB2_kernel(const float* __restrict__ w,
                                                     ushort* __restrict__ B2)
{
  const long long stride = (long long)gridDim.x * blockDim.x;
  for (long long i = (long long)blockIdx.x * blockDim.x + threadIdx.x;
       i < (long long)V_ * 512; i += stride) {
    int n = (int)(i >> 9), k = (int)(i & 511);
    float x = w[i];
    uint32_t hi = f2bf(x);
    float hf = __uint_as_float(hi << 16);
    uint32_t lo = f2bf(x - hf);
    ushort* row = B2 + (size_t)n * 1536;
    row[k] = (ushort)hi;
    row[512 + k] = (ushort)lo;
    row[1024 + k] = (ushort)hi;
  }
}

// ---------------- backbone: Linear + LayerNorm + exact GELU, state init ----------------
__global__ __launch_bounds__(256) void backbone_kernel(
    const float* __restrict__ x, const float* __restrict__ bb_w, const float* __restrict__ bb_b,
    const float* __restrict__ ln_g, const float* __restrict__ ln_b, const float* __restrict__ sos,
    ushort* __restrict__ A0a, ushort* __restrict__ A1a,
    float* __restrict__ c0, float* __restrict__ c1, int* __restrict__ done)
{
  const int b = blockIdx.x, tid = threadIdx.x;
  __shared__ float xs[E_];
  __shared__ float zs[H_];
  __shared__ float red[256];
  xs[tid] = x[b * E_ + tid];
  __syncthreads();
  for (int jj = 0; jj < 2; ++jj) {
    int j = jj * 256 + tid;
    float acc = 0.0f;
#pragma unroll 4
    for (int k = 0; k < E_; ++k) acc = fmaf(xs[k], bb_w[(size_t)j * E_ + k], acc);
    zs[j] = acc + bb_b[j];
  }
  __syncthreads();
  red[tid] = zs[tid] + zs[tid + 256];
  __syncthreads();
  for (int off = 128; off > 0; off >>= 1) { if (tid < off) red[tid] += red[tid + off]; __syncthreads(); }
  const float mu = red[0] / 512.0f;
  __syncthreads();
  {
    float d0 = zs[tid] - mu, d1 = zs[tid + 256] - mu;
    red[tid] = d0 * d0 + d1 * d1;
  }
  __syncthreads();
  for (int off = 128; off > 0; off >>= 1) { if (tid < off) red[tid] += red[tid + off]; __syncthreads(); }
  const float var = red[0] / 512.0f;
  const float sv = sqrtf(var + 1e-5f);
  for (int jj = 0; jj < 2; ++jj) {
    int j = jj * 256 + tid;
    float zn = (zs[j] - mu) / sv * ln_g[j] + ln_b[j];
    float h = 0.5f * zn * (1.0f + erff(zn / 1.41421356237309515f));
    uint32_t hi = f2bf(h);
    float hf = __uint_as_float(hi << 16);
    uint32_t lo = f2bf(h - hf);
    A0a[(size_t)b * 2304 + 256 + j]  = (ushort)hi;   // h0 hi (chunk0)
    A0a[(size_t)b * 2304 + 1024 + j] = (ushort)hi;   // h0 hi (chunk1)
    A0a[(size_t)b * 2304 + 1792 + j] = (ushort)lo;   // h0 lo (chunk2)
    A1a[(size_t)b * 3072 + 512 + j]  = 0;            // h1 = 0
    A1a[(size_t)b * 3072 + 1536 + j] = 0;
    A1a[(size_t)b * 3072 + 2560 + j] = 0;
    c0[(size_t)b * 512 + j] = 0.0f;
    c1[(size_t)b * 512 + j] = 0.0f;
  }
  {
    const float xv = sos[tid];
    uint32_t hi = f2bf(xv);
    float hf = __uint_as_float(hi << 16);
    uint32_t lo = f2bf(xv - hf);
    A0a[(size_t)b * 2304 + tid]        = (ushort)hi;  // x hi (chunk0)
    A0a[(size_t)b * 2304 + 768 + tid]  = (ushort)hi;  // x hi (chunk1)
    A0a[(size_t)b * 2304 + 1536 + tid] = (ushort)lo;  // x lo (chunk2)
  }
  if (tid == 0) done[b] = 0;
}

// ---------------- split-bf16 MFMA LSTM cell, double-buffered 2-phase ----------------
// A3 [256][K3], W3 [2048][K3] bf16; 32x64 tile, grid (32,8)=256 blocks, 4 waves (2x2).
// LDS per buffer: A 4KB @ +0, W 8KB @ +4KB; buffers at 0 / 12KB. Gate transpose aliases buf0.
template<int KC>
__global__ __launch_bounds__(256) void mfma_lstm(
    const ushort* __restrict__ A3, const ushort* __restrict__ W3,
    const float* __restrict__ bias, float* __restrict__ c,
    ushort* __restrict__ d1, int rs1, int o1a, int o1b, int o1c,
    ushort* __restrict__ d2, int rs2, int o2a, int o2b, int o2c)
{
  constexpr int K3 = KC * 64;
  __shared__ __align__(16) char smem[24576];
  char* lds = smem;
  const int tid = threadIdx.x;
  const int lane = tid & 63;
  const int wid = tid >> 6;
  const int wm = wid >> 1, wn = wid & 1;
  const int m0 = blockIdx.y * 32;
  const int n0 = blockIdx.x * 64;

  auto stage = [&](int kc, int base) {
    const int kus = kc * 64;
    {  // A tile [32][64]: 4 KB, 1 load/thread
      const int o = wid * 1024 + lane * 16;
      const int row = o >> 7;
      const int kb = (o >> 4) & 7;
      const int ksrc = kus + ((kb ^ (row & 7)) << 3);
      glds16(A3 + (size_t)(m0 + row) * K3 + ksrc, (void*)(lds + base + wid * 1024));
    }
#pragma unroll
    for (int s = 0; s < 2; ++s) {  // W tile [64][64]: 8 KB, 2 loads/thread
      const int o = (wid * 2 + s) * 1024 + lane * 16;
      const int row = o >> 7;
      const int kb = (o >> 4) & 7;
      const int ksrc = kus + ((kb ^ (row & 7)) << 3);
      glds16(W3 + (size_t)(n0 + row) * K3 + ksrc,
             (void*)(lds + base + 4096 + (wid * 2 + s) * 1024));
    }
  };

  f32x4 acc[2];
#pragma unroll
  for (int j = 0; j < 2; ++j)
#pragma unroll
    for (int q = 0; q < 4; ++q) acc[j][q] = 0.0f;

  stage(0, 0);
  asm volatile("s_waitcnt vmcnt(0)" ::: "memory");
  __syncthreads();
  for (int kc = 0; kc < KC; ++kc) {
    const int cb = (kc & 1) * 12288;
    if (kc + 1 < KC) stage(kc + 1, cb ^ 12288);
#pragma unroll
    for (int ks = 0; ks < 2; ++ks) {
      const int kb = ks * 4 + (lane >> 4);
      const int arow = wm * 16 + (lane & 15);
      bf16x8 a = *(const bf16x8*)(lds + cb + arow * 128 + ((kb ^ (arow & 7)) << 4));
      bf16x8 w[2];
#pragma unroll
      for (int j = 0; j < 2; ++j) {
        const int col = wn * 32 + j * 16 + (lane & 15);
        w[j] = *(const bf16x8*)(lds + cb + 4096 + col * 128 + ((kb ^ (col & 7)) << 4));
      }
#pragma unroll
      for (int j = 0; j < 2; ++j)
        acc[j] = __builtin_amdgcn_mfma_f32_16x16x32_bf16(a, w[j], acc[j], 0, 0, 0);
    }
    asm volatile("s_waitcnt vmcnt(0)" ::: "memory");
    __syncthreads();
  }
  // gate transpose via LDS (f32 [32][65], aliases buf0 — all reads done after final barrier)
  float* gls = (float*)smem;
#pragma unroll
  for (int j = 0; j < 2; ++j)
#pragma unroll
    for (int q = 0; q < 4; ++q)
      gls[(wm * 16 + (lane >> 4) * 4 + q) * 65 + wn * 32 + j * 16 + (lane & 15)] = acc[j][q];
  __syncthreads();
  const int row = tid >> 3;                  // 0..31
  const int m = m0 + row;
#pragma unroll
  for (int e = 0; e < 2; ++e) {
    const int ul = (tid & 7) * 2 + e;        // local unit 0..15
    const int nc = ul * 4;
    const float gi = gls[row * 65 + nc + 0] + bias[n0 + nc + 0];
    const float gf = gls[row * 65 + nc + 1] + bias[n0 + nc + 1];
    const float gg = gls[row * 65 + nc + 2] + bias[n0 + nc + 2];
    const float go = gls[row * 65 + nc + 3] + bias[n0 + nc + 3];
    const int u = (n0 >> 2) + ul;            // global hidden unit
    const float si = 1.0f / (1.0f + expf(-gi));
    const float sf = 1.0f / (1.0f + expf(-gf));
    const float so = 1.0f / (1.0f + expf(-go));
    const float cn = sf * c[(size_t)m * 512 + u] + si * tanhf(gg);
    const float hn = so * tanhf(cn);
    c[(size_t)m * 512 + u] = cn;
    const uint32_t hi = f2bf(hn);
    const float hf = __uint_as_float(hi << 16);
    const uint32_t lo = f2bf(hn - hf);
    d1[(size_t)m * rs1 + o1a + u] = (ushort)hi;
    d1[(size_t)m * rs1 + o1b + u] = (ushort)hi;
    d1[(size_t)m * rs1 + o1c + u] = (ushort)lo;
    d2[(size_t)m * rs2 + o2a + u] = (ushort)hi;
    d2[(size_t)m * rs2 + o2b + u] = (ushort)hi;
    d2[(size_t)m * rs2 + o2c + u] = (ushort)lo;
  }
}

// ---------------- bf16 MFMA logits GEMM, double-buffered 2-phase ----------------
// [256][1536] x [32000][1536]^T + bias -> f32. 128x128 tile, 4 waves (2x2), 4x4 frags.
// LDS 64 KB: buf{0,1} x {A 16KB, B 16KB}. XCD-bijective swizzle + m-pair adjacency.
__global__ __launch_bounds__(256) void mfma_logits(
    const ushort* __restrict__ A2,   // [256][1536] bf16
    const ushort* __restrict__ B2,   // [32000][1536] bf16
    const float* __restrict__ bias,  // [32000]
    float* __restrict__ logits)      // [256][32000] f32
{
  __shared__ __align__(16) char smem[65536];
  char* lds = smem;
  const int tid = threadIdx.x;
  const int lane = tid & 63;
  const int wid = tid >> 6;
  const int wm = wid >> 1, wn = wid & 1;
  // bijective XCD swizzle (nwg=500: q=62, r=4), then m-blocks of a panel adjacent
  const int bid = blockIdx.x;
  const int xcd = bid & 7, idx = bid >> 3;
  const int wg = (xcd < 4 ? xcd * 63 : 252 + (xcd - 4) * 62) + idx;
  const int m0 = (wg & 1) * 128;
  const int n0 = (wg >> 1) * 128;

  auto stage = [&](int kc, int base) {
    const int kus = kc * 64;
#pragma unroll
    for (int s = 0; s < 4; ++s) {
      const int o = (wid * 4 + s) * 1024 + lane * 16;
      const int row = o >> 7;
      const int kb = (o >> 4) & 7;
      const int ksrc = kus + ((kb ^ (row & 7)) << 3);
      glds16(A2 + (size_t)(m0 + row) * 1536 + ksrc,
             (void*)(lds + base + (wid * 4 + s) * 1024));
      glds16(B2 + (size_t)(n0 + row) * 1536 + ksrc,
             (void*)(lds + base + 16384 + (wid * 4 + s) * 1024));
    }
  };

  f32x4 acc[4][4];
#pragma unroll
  for (int i = 0; i < 4; ++i)
#pragma unroll
    for (int j = 0; j < 4; ++j)
#pragma unroll
      for (int q = 0; q < 4; ++q) acc[i][j][q] = 0.0f;

  stage(0, 0);
  asm volatile("s_waitcnt vmcnt(0)" ::: "memory");
  __syncthreads();
  for (int kc = 0; kc < 24; ++kc) {
    const int cb = (kc & 1) * 32768;
    if (kc + 1 < 24) stage(kc + 1, cb ^ 32768);
#pragma unroll
    for (int ks = 0; ks < 2; ++ks) {
      bf16x8 a[4], b[4];
      const int kb = ks * 4 + (lane >> 4);
#pragma unroll
      for (int i = 0; i < 4; ++i) {
        const int row = wm * 64 + i * 16 + (lane & 15);
        a[i] = *(const bf16x8*)(lds + cb + row * 128 + ((kb ^ (row & 7)) << 4));
        const int col = wn * 64 + i * 16 + (lane & 15);
        b[i] = *(const bf16x8*)(lds + cb + 16384 + col * 128 + ((kb ^ (col & 7)) << 4));
      }
#pragma unroll
      for (int i = 0; i < 4; ++i)
#pragma unroll
        for (int j = 0; j < 4; ++j)
          acc[i][j] = __builtin_amdgcn_mfma_f32_16x16x32_bf16(a[i], b[j], acc[i][j], 0, 0, 0);
    }
    asm volatile("s_waitcnt vmcnt(0)" ::: "memory");
    __syncthreads();
  }
  float bj[4];
#pragma unroll
  for (int j = 0; j < 4; ++j) bj[j] = bias[n0 + wn * 64 + j * 16 + (lane & 15)];
  const int rbase = (lane >> 4) * 4;
#pragma unroll
  for (int i = 0; i < 4; ++i) {
    const int m = m0 + wm * 64 + i * 16 + rbase;
#pragma unroll
    for (int j = 0; j < 4; ++j) {
      const int n = n0 + wn * 64 + j * 16 + (lane & 15);
#pragma unroll
      for (int q = 0; q < 4; ++q)
        logits[(size_t)(m + q) * V_ + n] = acc[i][j][q] + bj[j];
    }
  }
}

// ---------------- sample_row: one pass (m=0), fused feedback as bf16 triple ----------------
__global__ __launch_bounds__(512) void sample_row(
    const float* __restrict__ logits, const uint32_t* __restrict__ keys, int t,
    const float* __restrict__ emb, int* __restrict__ done,
    ushort* __restrict__ A0next, float* __restrict__ ids,
    float* __restrict__ logp, float* __restrict__ ent, float* __restrict__ lens)
{
  const int b = blockIdx.x, tid = threadIdx.x;
  const uint32_t k0 = keys[2 * t], k1 = keys[2 * t + 1];
  const float* lrow = logits + (size_t)b * V_;

  float S = 0.0f, Aa = 0.0f, sb = -INFINITY, lb = 0.0f; int ib = 0;
  for (int idx = tid; idx < V_ / 4; idx += 512) {
    float4 l4 = *(const float4*)&lrow[idx * 4];
    const float le[4] = {l4.x, l4.y, l4.z, l4.w};
#pragma unroll
    for (int e = 0; e < 4; ++e) {
      const int v = idx * 4 + e;
      uint32_t o0, o1;
      tf2x32(k0, k1, 0u, (uint32_t)(b * V_ + v), o0, o1);
      const float s = le[e] + gumbel_from_bits(o0 ^ o1);
      if (s > sb) { sb = s; ib = v; lb = le[e]; }
      const float ex = expf(le[e]);          // |l| < ~1: no overflow, skip max-shift
      S += ex; Aa = fmaf(ex, le[e], Aa);
    }
  }
  __shared__ float ss[512], sa[512], sv[512], sl[512];
  __shared__ int si[512];
  ss[tid] = S; sa[tid] = Aa; sv[tid] = sb; si[tid] = ib; sl[tid] = lb;
  __syncthreads();
  for (int o = 256; o > 0; o >>= 1) {
    if (tid < o) {
      ss[tid] += ss[tid + o]; sa[tid] += sa[tid + o];
      float v2 = sv[tid + o]; int i2 = si[tid + o];
      if (v2 > sv[tid] || (v2 == sv[tid] && i2 < si[tid])) {
        sv[tid] = v2; si[tid] = i2; sl[tid] = sl[tid + o];
      }
    }
    __syncthreads();
  }
  if (tid == 0) {
    const float Ssum = ss[0], Asum = sa[0];
    const float logS = logf(Ssum);
    const int tok = si[0];
    const float lp = sl[0] - logS;
    const float en = logS - Asum / Ssum;
    const int dn = done[b];
    const int tokm = dn ? 0 : tok;
    ids[b * T_ + t]  = (float)tokm;
    logp[b * T_ + t] = dn ? 0.0f : lp;
    ent[b * T_ + t]  = dn ? 0.0f : en;
    done[b] = dn | (tokm == 0);
    si[0] = tokm;
    if (t == T_ - 1) {
      int len = T_; bool has = false;
      for (int tt = 0; tt < T_; ++tt) {
        if (!has && ids[b * T_ + tt] == 0.0f) { has = true; len = tt + 1; }
      }
      for (int tt = len - 1; tt < T_; ++tt) ids[b * T_ + tt] = 0.0f;
      lens[b] = (float)len;
    }
  }
  __syncthreads();
  const int tk = si[0];
  if (tid < E_) {
    const float xv = emb[(size_t)tk * E_ + tid];
    const uint32_t hi = f2bf(xv);
    const float hf = __uint_as_float(hi << 16);
    const uint32_t lo = f2bf(xv - hf);
    A0next[(size_t)b * 2304 + tid]        = (ushort)hi;
    A0next[(size_t)b * 2304 + 768 + tid]  = (ushort)hi;
    A0next[(size_t)b * 2304 + 1536 + tid] = (ushort)lo;
  }
}

// ---------------- one-hot msg fill ----------------
__global__ __launch_bounds__(256) void msg_kernel(const float* __restrict__ ids,
                                                  float* __restrict__ msg) {
  const int bt = blockIdx.x;            // 4096 = B*T
  const int id = (int)ids[bt];
  float4* dst = (float4*)(msg + (size_t)bt * V_);
  for (int q = threadIdx.x; q < V_ / 4; q += 256) {
    const int v = q * 4;
    float4 val;
    val.x = (v     == id) ? 1.0f : 0.0f;
    val.y = (v + 1 == id) ? 1.0f : 0.0f;
    val.z = (v + 2 == id) ? 1.0f : 0.0f;
    val.w = (v + 3 == id) ? 1.0f : 0.0f;
    dst[q] = val;
  }
}

// ---------------- launcher ----------------
extern "C" void kernel_launch(void* const* d_in, const int* in_sizes, int n_in,
                              void* d_out, int out_size, void* d_ws, size_t ws_size,
                              hipStream_t stream) {
  const float* x    = (const float*)d_in[0];
  const float* bb_w = (const float*)d_in[1];
  const float* bb_b = (const float*)d_in[2];
  const float* ln_g = (const float*)d_in[3];
  const float* ln_b = (const float*)d_in[4];
  const float* emb  = (const float*)d_in[5];
  const float* sos  = (const float*)d_in[6];
  const float* wih0 = (const float*)d_in[7];
  const float* whh0 = (const float*)d_in[8];
  const float* bih0 = (const float*)d_in[9];
  const float* bhh0 = (const float*)d_in[10];
  const float* wih1 = (const float*)d_in[11];
  const float* whh1 = (const float*)d_in[12];
  const float* bih1 = (const float*)d_in[13];
  const float* bhh1 = (const float*)d_in[14];
  const float* out_w = (const float*)d_in[15];
  const float* out_b = (const float*)d_in[16];

  float* out  = (float*)d_out;
  float* ids  = out;                                  // [B,T]   4096
  float* msg  = out + 4096;                           // [B,T,V] 131072000
  float* logp = out + 131076096;                      // [B,T]   4096
  float* ent  = out + 131080192;                      // [B,T]   4096
  float* lens = out + 131084288;                      // [B]     256

  // scratch inside msg region (rewritten at the end); all float-count offsets
  float* p = msg;
  ushort* W30 = (ushort*)p; p += 2359296;             // 2048*2304 bf16
  ushort* W31 = (ushort*)p; p += 3145728;             // 2048*3072 bf16
  float* bq0 = p; p += 2048;
  float* bq1 = p; p += 2048;
  ushort* A0a = (ushort*)p; p += 294912;              // 256*2304 bf16
  ushort* A0b = (ushort*)p; p += 294912;
  ushort* A1a = (ushort*)p; p += 393216;              // 256*3072 bf16
  ushort* A1b = (ushort*)p; p += 393216;
  float* c0 = p; p += 131072;
  float* c1 = p; p += 131072;
  ushort* A2 = (ushort*)p; p += 196608;               // 256*1536 bf16
  ushort* B2 = (ushort*)p; p += 24576000;             // 32000*1536 bf16
  float* logits = p; p += 8192000;                    // 256*32000 f32
  uint32_t* keys = (uint32_t*)p; p += 64;
  int* done = (int*)p; p += 256;

  prepW3_kernel<<<2048, 256, 0, stream>>>(wih0, whh0, bih0, bhh0, W30, bq0, 256, keys);
  prepW3_kernel<<<2048, 256, 0, stream>>>(wih1, whh1, bih1, bhh1, W31, bq1, 512, nullptr);
  prepB2_kernel<<<4096, 256, 0, stream>>>(out_w, B2);
  backbone_kernel<<<256, 256, 0, stream>>>(x, bb_w, bb_b, ln_g, ln_b, sos,
                                           A0a, A1a, c0, c1, done);
  for (int t = 0; t < T_; ++t) {
    ushort* A0c = (t & 1) ? A0b : A0a;
    ushort* A0n = (t & 1) ? A0a : A0b;
    ushort* A1c = (t & 1) ? A1b : A1a;
    ushort* A1n = (t & 1) ? A1a : A1b;
    // cell 0: h0 -> A1 cur (h0 slots) + A0 next (h slots)
    mfma_lstm<36><<<dim3(32, 8), 256, 0, stream>>>(
        A0c, W30, bq0, c0,
        A1c, 3072, 0, 1024, 2048,
        A0n, 2304, 256, 1024, 1792);
    // cell 1: h1 -> A1 next (h1 slots) + A2 (logits input)
    mfma_lstm<48><<<dim3(32, 8), 256, 0, stream>>>(
        A1c, W31, bq1, c1,
        A1n, 3072, 512, 1536, 2560,
        A2, 1536, 0, 512, 1024);
    // logits (f32, materialized), double-buffered
    mfma_logits<<<500, 256, 0, stream>>>(A2, B2, out_b, logits);
    // fused sampling: one pass, argmax + softmax stats + feedback (+lengths at t=15)
    sample_row<<<256, 512, 0, stream>>>(logits, keys, t, emb, done,
                                        A0n, ids, logp, ent, lens);
  }
  msg_kernel<<<4096, 256, 0, stream>>>(ids, msg);
}